// Round 2
// baseline (1120.769 us; speedup 1.0000x reference)
//
#include <hip/hip_runtime.h>
#include <hip/hip_bf16.h>
#include <stdint.h>

#define DEV static __device__ __forceinline__

DEV float bf2f(unsigned short u) { return __uint_as_float(((unsigned)u) << 16); }
DEV unsigned short f2bf(float f) {
    unsigned u = __float_as_uint(f);
    u += 0x7fff + ((u >> 16) & 1);   // RNE
    return (unsigned short)(u >> 16);
}

// ---------------- dtype detection ----------------
// flags[0] = 1 if float tensors are bf16, 0 if fp32
// flags[1] = 1 if edge_index is int64, 0 if int32

__global__ void k_detect(const unsigned* __restrict__ xw, const int* __restrict__ ei,
                         int* __restrict__ flags) {
    if (threadIdx.x == 0 && blockIdx.x == 0) {
        int pass = 0;
        for (int i = 0; i < 128; ++i) {
            unsigned lo = xw[i] & 0xFFFFu;            // bf16 candidate
            int e = (lo >> 7) & 0xFF;                 // exponent field
            if (e >= 112 && e <= 135) ++pass;         // |v| in [2^-15, 2^8]
        }
        flags[0] = (pass >= 64) ? 1 : 0;
        int zeros = 0;
        for (int i = 0; i < 128; ++i) if (ei[2 * i + 1] == 0) ++zeros;
        flags[1] = (zeros >= 64) ? 1 : 0;
    }
}

// widen bf16 -> fp32, or copy fp32 -> fp32, per flags[0]
__global__ void k_cvt(const void* __restrict__ src, float* __restrict__ dst, int n,
                      const int* __restrict__ flags) {
    int i = blockIdx.x * 256 + threadIdx.x;
    if (i >= n) return;
    if (flags[0]) dst[i] = bf2f(((const unsigned short*)src)[i]);
    else          dst[i] = ((const float*)src)[i];
}

// narrow edge_index to int32 src/dst arrays, per flags[1]
__global__ void k_cvt_idx(const int* __restrict__ ei, int* __restrict__ src32,
                          int* __restrict__ dst32, int E, const int* __restrict__ flags) {
    int i = blockIdx.x * 256 + threadIdx.x;
    if (i >= E) return;
    if (flags[1]) { src32[i] = ei[2 * i]; dst32[i] = ei[2 * E + 2 * i]; }
    else          { src32[i] = ei[i];     dst32[i] = ei[E + i]; }
}

// ---------------- CSR build ----------------

__global__ void k_degree(const int* __restrict__ dst, int* __restrict__ deg, int E) {
    int i = blockIdx.x * 256 + threadIdx.x;
    if (i < E) atomicAdd(&deg[dst[i]], 1);
}

__global__ void k_scan(const int* __restrict__ deg, int* __restrict__ row_ptr, int n) {
    __shared__ int s[1024];
    __shared__ int carry;
    int t = threadIdx.x;
    if (t == 0) carry = 0;
    __syncthreads();
    for (int base = 0; base < n; base += 1024) {
        int i = base + t;
        int v = (i < n) ? deg[i] : 0;
        s[t] = v;
        __syncthreads();
        for (int off = 1; off < 1024; off <<= 1) {
            int tmp = (t >= off) ? s[t - off] : 0;
            __syncthreads();
            s[t] += tmp;
            __syncthreads();
        }
        if (i < n) row_ptr[i] = carry + s[t] - v;   // exclusive
        __syncthreads();
        if (t == 0) carry += s[1023];
        __syncthreads();
    }
    if (t == 0) row_ptr[n] = carry;
}

__global__ void k_fill(const int* __restrict__ src, const int* __restrict__ dst,
                       const int* __restrict__ row_ptr, int* __restrict__ cursor,
                       int* __restrict__ csr, int E) {
    int i = blockIdx.x * 256 + threadIdx.x;
    if (i < E) {
        int d = dst[i];
        int p = atomicAdd(&cursor[d], 1);
        csr[row_ptr[d] + p] = src[i];
    }
}

// ---------------- mean aggregation: one wave per node ----------------

template<int D>
__global__ void k_aggr(const float* __restrict__ xin, const int* __restrict__ row_ptr,
                       const int* __restrict__ csr, float* __restrict__ agg, int n) {
    int wid = (blockIdx.x * blockDim.x + threadIdx.x) >> 6;
    int lane = threadIdx.x & 63;
    if (wid >= n) return;
    constexpr int V = D / 64;
    double acc[V];
#pragma unroll
    for (int i = 0; i < V; ++i) acc[i] = 0.0;
    int s0 = row_ptr[wid], s1 = row_ptr[wid + 1];
    for (int j = s0; j < s1; ++j) {
        int s = csr[j];
        const float* p = xin + (size_t)s * D + lane;
#pragma unroll
        for (int i = 0; i < V; ++i) acc[i] += (double)p[i * 64];
    }
    double inv = 1.0 / (double)max(s1 - s0, 1);
#pragma unroll
    for (int i = 0; i < V; ++i) agg[(size_t)wid * D + i * 64 + lane] = (float)(acc[i] * inv);
}

// ---------------- gate: logits -> softmax std, argmax, expert histogram ----------------

template<int D>
__global__ void k_gate(const float* __restrict__ agg, const float* __restrict__ wg,
                       const float* __restrict__ bg, int* __restrict__ idx,
                       int* __restrict__ ecnt, float* __restrict__ gsum, int n) {
    __shared__ float swg[D * 8];
    __shared__ int hcnt[8];
    __shared__ float red[256];
    int t = threadIdx.x;
    if (t < 8) hcnt[t] = 0;
    for (int i = t; i < D * 8; i += 256) swg[i] = wg[i];
    __syncthreads();
    int nid = blockIdx.x * 256 + t;
    float stdv = 0.f;
    if (nid < n) {
        double lg[8];
#pragma unroll
        for (int e = 0; e < 8; ++e) lg[e] = (double)bg[e];
        const float* ap = agg + (size_t)nid * D;
        for (int k = 0; k < D; k += 4) {
            float4 a = *(const float4*)(ap + k);
#pragma unroll
            for (int e = 0; e < 8; ++e) {
                lg[e] += (double)a.x * swg[(k + 0) * 8 + e] + (double)a.y * swg[(k + 1) * 8 + e]
                       + (double)a.z * swg[(k + 2) * 8 + e] + (double)a.w * swg[(k + 3) * 8 + e];
            }
        }
        double m = lg[0];
        int am = 0;
#pragma unroll
        for (int e = 1; e < 8; ++e) if (lg[e] > m) { m = lg[e]; am = e; }
        double s = 0.0, p[8];
#pragma unroll
        for (int e = 0; e < 8; ++e) { p[e] = exp(lg[e] - m); s += p[e]; }
        double invs = 1.0 / s, sq = 0.0;
#pragma unroll
        for (int e = 0; e < 8; ++e) { double q = p[e] * invs; sq += q * q; }
        stdv = (float)sqrt(fmax(sq - 0.125, 0.0) / 7.0);
        idx[nid] = am;
        atomicAdd(&hcnt[am], 1);
    }
    red[t] = stdv;
    __syncthreads();
    for (int off = 128; off > 0; off >>= 1) {
        if (t < off) red[t] += red[t + off];
        __syncthreads();
    }
    if (t == 0) atomicAdd(gsum, red[0]);
    if (t < 8 && hcnt[t] > 0) atomicAdd(&ecnt[t], hcnt[t]);
}

__global__ void k_offsets(const int* __restrict__ ecnt, int* __restrict__ eoff) {
    if (threadIdx.x == 0 && blockIdx.x == 0) {
        int s = 0;
        for (int e = 0; e < 8; ++e) { eoff[e] = s; s += ecnt[e]; }
        eoff[8] = s;
    }
}

__global__ void k_perm(const int* __restrict__ idx, const int* __restrict__ eoff,
                       int* __restrict__ ecur, int* __restrict__ perm, int n) {
    __shared__ int lcnt[8], lbase[8];
    int t = threadIdx.x;
    if (t < 8) lcnt[t] = 0;
    __syncthreads();
    int nid = blockIdx.x * 256 + t;
    int e = 0, r = 0;
    bool valid = (nid < n);
    if (valid) { e = idx[nid]; r = atomicAdd(&lcnt[e], 1); }
    __syncthreads();
    if (t < 8) lbase[t] = lcnt[t] ? atomicAdd(&ecur[t], lcnt[t]) : 0;
    __syncthreads();
    if (valid) perm[eoff[e] + lbase[e] + r] = nid;
}

// ---------------- fused GEMM: out = [agg | a2] @ [B1 ; B2] + bias (+relu) ----------------
// 64-row x NCOL tile per block, rows gathered via perm (expert-grouped) or identity.
// outflags != nullptr: final layer; store bf16 if outflags[0] else fp32.

template<int DIN, int NCOL, bool EXPERT, bool RELU>
__global__ __launch_bounds__(256) void k_gemm(
    const float* __restrict__ agg, const float* __restrict__ a2,
    const float* __restrict__ B1, const float* __restrict__ B2,
    const float* __restrict__ bias,
    const int* __restrict__ perm, const int* __restrict__ eoff,
    void* __restrict__ outp, const int* __restrict__ outflags, int n) {
    constexpr int CT = NCOL / 4;     // threads along columns
    constexpr int RG = 256 / CT;     // row groups
    constexpr int RPT = 64 / RG;     // rows per thread
    __shared__ float a_tile[64 * 64];
    __shared__ int rows[64];
    int t = threadIdx.x;
    int e = 0, base = 0, cnt = n;
    if (EXPERT) { e = blockIdx.y; base = eoff[e]; cnt = eoff[e + 1] - base; }
    int rs = blockIdx.x * 64;
    if (rs >= cnt) return;
    int nrows = min(64, cnt - rs);
    if (t < 64) {
        int j = rs + min(t, nrows - 1);
        rows[t] = EXPERT ? perm[base + j] : j;
    }
    __syncthreads();
    int cg = t % CT, rg = t / CT;
    int cols = cg * 4;
    int sr = t >> 2;
    int sk = (t & 3) * 16;
    int grow = rows[sr];
    const float* B1e = B1 + (EXPERT ? (size_t)e * DIN * NCOL : 0);
    float acc[RPT][4];
#pragma unroll
    for (int r = 0; r < RPT; ++r) { acc[r][0] = 0.f; acc[r][1] = 0.f; acc[r][2] = 0.f; acc[r][3] = 0.f; }

#pragma unroll
    for (int half = 0; half < 2; ++half) {
        const float* B = half ? B2 : B1e;
        const float* Af = half ? a2 : agg;
        for (int kc = 0; kc < DIN; kc += 64) {
            __syncthreads();
            {
                const float4* p = (const float4*)(Af + (size_t)grow * DIN + kc + sk);
                float4* d4 = (float4*)&a_tile[sr * 64 + sk];
                d4[0] = p[0]; d4[1] = p[1]; d4[2] = p[2]; d4[3] = p[3];
            }
            __syncthreads();
            const float* Bp = B + (size_t)kc * NCOL + cols;
            for (int k = 0; k < 64; k += 4) {
                float bx[4][4];
#pragma unroll
                for (int kk = 0; kk < 4; ++kk) {
                    float4 br = *(const float4*)(Bp + (size_t)(k + kk) * NCOL);
                    bx[kk][0] = br.x; bx[kk][1] = br.y; bx[kk][2] = br.z; bx[kk][3] = br.w;
                }
#pragma unroll
                for (int r = 0; r < RPT; ++r) {
                    float4 a = *(const float4*)&a_tile[(rg * RPT + r) * 64 + k];
#pragma unroll
                    for (int c = 0; c < 4; ++c) {
                        acc[r][c] = fmaf(a.x, bx[0][c], acc[r][c]);
                        acc[r][c] = fmaf(a.y, bx[1][c], acc[r][c]);
                        acc[r][c] = fmaf(a.z, bx[2][c], acc[r][c]);
                        acc[r][c] = fmaf(a.w, bx[3][c], acc[r][c]);
                    }
                }
            }
        }
    }
    float4 bb = *(const float4*)(bias + (EXPERT ? e * NCOL : 0) + cols);
    bool obf = (outflags != nullptr) && (outflags[0] != 0);
#pragma unroll
    for (int r = 0; r < RPT; ++r) {
        int rr = rg * RPT + r;
        if (rr < nrows) {
            int gr = rows[rr];
            float v0 = acc[r][0] + bb.x, v1 = acc[r][1] + bb.y;
            float v2 = acc[r][2] + bb.z, v3 = acc[r][3] + bb.w;
            if (RELU) { v0 = fmaxf(v0, 0.f); v1 = fmaxf(v1, 0.f); v2 = fmaxf(v2, 0.f); v3 = fmaxf(v3, 0.f); }
            if (outflags == nullptr) {
                *(float4*)((float*)outp + (size_t)gr * NCOL + cols) = make_float4(v0, v1, v2, v3);
            } else if (obf) {
                unsigned lo = (unsigned)f2bf(v0) | ((unsigned)f2bf(v1) << 16);
                unsigned hi = (unsigned)f2bf(v2) | ((unsigned)f2bf(v3) << 16);
                *(uint2*)((unsigned short*)outp + (size_t)gr * NCOL + cols) = make_uint2(lo, hi);
            } else {
                *(float4*)((float*)outp + (size_t)gr * NCOL + cols) = make_float4(v0, v1, v2, v3);
            }
        }
    }
}

__global__ void k_final(const float* __restrict__ gsum, void* __restrict__ outp,
                        const int* __restrict__ flags) {
    if (threadIdx.x == 0 && blockIdx.x == 0) {
        float g = (gsum[0] + gsum[1]) * (0.5f / 50000.0f);
        if (flags[0]) ((unsigned short*)outp)[(size_t)50000 * 128] = f2bf(g);
        else          ((float*)outp)[(size_t)50000 * 128] = g;
    }
}

extern "C" void kernel_launch(void* const* d_in, const int* in_sizes, int n_in,
                              void* d_out, int out_size, void* d_ws, size_t ws_size,
                              hipStream_t stream) {
    constexpr int N = 50000, E = 800000;
    const int* ei = (const int*)d_in[1];

    // ---- workspace layout (ints first, then 256-aligned floats) ----
    int* ip = (int*)d_ws;
    int* deg = ip;            ip += N;
    int* cursor = ip;         ip += N;
    int* ecnt = ip;           ip += 16;           // 2 layers x 8
    int* ecur = ip;           ip += 16;
    float* gsum = (float*)ip; ip += 2;
    int* flags = ip;          ip += 2;
    int* row_ptr = ip;        ip += N + 1;
    int* csr = ip;            ip += E;
    int* idxb = ip;           ip += N;
    int* permb = ip;          ip += N;
    int* eoff = ip;           ip += 18;           // 2 layers x 9
    int* src32 = ip;          ip += E;
    int* dst32 = ip;          ip += E;
    size_t off = (size_t)((char*)ip - (char*)d_ws);
    off = (off + 255) & ~(size_t)255;
    float* fp = (float*)((char*)d_ws + off);
    float* xf   = fp; fp += (size_t)N * 128;
    float* wg1f = fp; fp += 128 * 8;
    float* bg1f = fp; fp += 8;
    float* we1f = fp; fp += 8 * 128 * 256;
    float* be1f = fp; fp += 8 * 256;
    float* wr1f = fp; fp += 128 * 256;
    float* wg2f = fp; fp += 256 * 8;
    float* bg2f = fp; fp += 8;
    float* we2f = fp; fp += 8 * 256 * 256;
    float* be2f = fp; fp += 8 * 256;
    float* wr2f = fp; fp += 256 * 256;
    float* wl3f = fp; fp += 256 * 128;
    float* bl3f = fp; fp += 128;
    float* wr3f = fp; fp += 256 * 128;
    float* agg = fp; fp += (size_t)N * 256;
    float* h1  = fp; fp += (size_t)N * 256;
    float* h2  = fp; fp += (size_t)N * 256;

    hipMemsetAsync(d_ws, 0, (size_t)(2 * N + 34) * 4, stream);

    // ---- dtype detection + conversion to fp32 ----
    k_detect<<<1, 64, 0, stream>>>((const unsigned*)d_in[0], ei, flags);
    struct { const void* s; float* d; int n; } cv[14] = {
        { d_in[0],  xf,   N * 128 },
        { d_in[2],  wg1f, 128 * 8 },   { d_in[3],  bg1f, 8 },
        { d_in[4],  we1f, 8 * 128 * 256 }, { d_in[5],  be1f, 8 * 256 },
        { d_in[6],  wr1f, 128 * 256 },
        { d_in[7],  wg2f, 256 * 8 },   { d_in[8],  bg2f, 8 },
        { d_in[9],  we2f, 8 * 256 * 256 }, { d_in[10], be2f, 8 * 256 },
        { d_in[11], wr2f, 256 * 256 },
        { d_in[12], wl3f, 256 * 128 }, { d_in[13], bl3f, 128 },
        { d_in[14], wr3f, 256 * 128 },
    };
    for (int i = 0; i < 14; ++i)
        k_cvt<<<(cv[i].n + 255) / 256, 256, 0, stream>>>(cv[i].s, cv[i].d, cv[i].n, flags);
    k_cvt_idx<<<(E + 255) / 256, 256, 0, stream>>>(ei, src32, dst32, E, flags);

    // ---- CSR ----
    k_degree<<<(E + 255) / 256, 256, 0, stream>>>(dst32, deg, E);
    k_scan<<<1, 1024, 0, stream>>>(deg, row_ptr, N);
    k_fill<<<(E + 255) / 256, 256, 0, stream>>>(src32, dst32, row_ptr, cursor, csr, E);

    // ---- layer 1: 128 -> 256, MoE + root(x), relu ----
    k_aggr<128><<<(N + 3) / 4, 256, 0, stream>>>(xf, row_ptr, csr, agg, N);
    k_gate<128><<<(N + 255) / 256, 256, 0, stream>>>(agg, wg1f, bg1f, idxb, ecnt, gsum, N);
    k_offsets<<<1, 1, 0, stream>>>(ecnt, eoff);
    k_perm<<<(N + 255) / 256, 256, 0, stream>>>(idxb, eoff, ecur, permb, N);
    k_gemm<128, 256, true, true><<<dim3((N + 63) / 64, 8), 256, 0, stream>>>(
        agg, xf, we1f, wr1f, be1f, permb, eoff, h1, nullptr, N);

    // ---- layer 2: 256 -> 256, MoE + root(h1), relu ----
    k_aggr<256><<<(N + 3) / 4, 256, 0, stream>>>(h1, row_ptr, csr, agg, N);
    k_gate<256><<<(N + 255) / 256, 256, 0, stream>>>(agg, wg2f, bg2f, idxb, ecnt + 8, gsum + 1, N);
    k_offsets<<<1, 1, 0, stream>>>(ecnt + 8, eoff + 9);
    k_perm<<<(N + 255) / 256, 256, 0, stream>>>(idxb, eoff + 9, ecur + 8, permb, N);
    k_gemm<256, 256, true, true><<<dim3((N + 63) / 64, 8), 256, 0, stream>>>(
        agg, h1, we2f, wr2f, be2f, permb, eoff + 9, h2, nullptr, N);

    // ---- layer 3: plain SAGE 256 -> 128, bias, no relu ----
    k_aggr<256><<<(N + 3) / 4, 256, 0, stream>>>(h2, row_ptr, csr, agg, N);
    k_gemm<256, 128, false, false><<<dim3((N + 63) / 64, 1), 256, 0, stream>>>(
        agg, h2, wl3f, wr3f, bl3f, nullptr, nullptr, d_out, flags, N);

    k_final<<<1, 1, 0, stream>>>(gsum, d_out, flags);
}

// Round 5
// 908.911 us; speedup vs baseline: 1.2331x; 1.2331x over previous
//
#include <hip/hip_runtime.h>
#include <hip/hip_bf16.h>
#include <stdint.h>

#define DEV static __device__ __forceinline__

typedef __attribute__((ext_vector_type(8))) short short8;   // 8 bf16 (4 VGPRs)
typedef __attribute__((ext_vector_type(4))) float f32x4;    // MFMA accumulator

DEV float bf2f(unsigned short u) { return __uint_as_float(((unsigned)u) << 16); }
DEV unsigned short f2bf(float f) {
    unsigned u = __float_as_uint(f);
    u += 0x7fff + ((u >> 16) & 1);   // RNE
    return (unsigned short)(u >> 16);
}

// ---------------- dtype detection ----------------
__global__ void k_detect(const unsigned* __restrict__ xw, const int* __restrict__ ei,
                         int* __restrict__ flags) {
    if (threadIdx.x == 0 && blockIdx.x == 0) {
        int pass = 0;
        for (int i = 0; i < 128; ++i) {
            unsigned lo = xw[i] & 0xFFFFu;
            int e = (lo >> 7) & 0xFF;
            if (e >= 112 && e <= 135) ++pass;
        }
        flags[0] = (pass >= 64) ? 1 : 0;
        int zeros = 0;
        for (int i = 0; i < 128; ++i) if (ei[2 * i + 1] == 0) ++zeros;
        flags[1] = (zeros >= 64) ? 1 : 0;
    }
}

__global__ void k_cvt(const void* __restrict__ src, float* __restrict__ dst, int n,
                      const int* __restrict__ flags) {
    int i = blockIdx.x * 256 + threadIdx.x;
    if (i >= n) return;
    if (flags[0]) dst[i] = bf2f(((const unsigned short*)src)[i]);
    else          dst[i] = ((const float*)src)[i];
}

__global__ void k_cvt_bf(const void* __restrict__ src, unsigned short* __restrict__ dst, int n,
                         const int* __restrict__ flags) {
    int i = blockIdx.x * 256 + threadIdx.x;
    if (i >= n) return;
    if (flags[0]) dst[i] = ((const unsigned short*)src)[i];
    else          dst[i] = f2bf(((const float*)src)[i]);
}

__global__ void k_cvt_idx(const int* __restrict__ ei, int* __restrict__ src32,
                          int* __restrict__ dst32, int E, const int* __restrict__ flags) {
    int i = blockIdx.x * 256 + threadIdx.x;
    if (i >= E) return;
    if (flags[1]) { src32[i] = ei[2 * i]; dst32[i] = ei[2 * E + 2 * i]; }
    else          { src32[i] = ei[i];     dst32[i] = ei[E + i]; }
}

// ---------------- weight transpose: out[c][r] = in[r][c], bf16 source, 32x32 tiles ----------------
__global__ void k_transpose(const unsigned short* __restrict__ in, unsigned short* __restrict__ out,
                            int R, int C) {
    __shared__ unsigned short tile[32][33];
    int tx = threadIdx.x & 31, ty = threadIdx.x >> 5;
    size_t mat = (size_t)blockIdx.z * R * C;
    int r0 = blockIdx.y * 32, c0 = blockIdx.x * 32;
#pragma unroll
    for (int j = 0; j < 32; j += 8)
        tile[ty + j][tx] = in[mat + (size_t)(r0 + ty + j) * C + c0 + tx];
    __syncthreads();
#pragma unroll
    for (int j = 0; j < 32; j += 8)
        out[mat + (size_t)(c0 + ty + j) * R + r0 + tx] = tile[tx][ty + j];
}

// ---------------- CSR build ----------------
__global__ void k_degree(const int* __restrict__ dst, int* __restrict__ deg, int E) {
    int i = blockIdx.x * 256 + threadIdx.x;
    if (i < E) atomicAdd(&deg[dst[i]], 1);
}

__global__ void k_scan(const int* __restrict__ deg, int* __restrict__ row_ptr, int n) {
    __shared__ int s[1024];
    __shared__ int carry;
    int t = threadIdx.x;
    if (t == 0) carry = 0;
    __syncthreads();
    for (int base = 0; base < n; base += 1024) {
        int i = base + t;
        int v = (i < n) ? deg[i] : 0;
        s[t] = v;
        __syncthreads();
        for (int off = 1; off < 1024; off <<= 1) {
            int tmp = (t >= off) ? s[t - off] : 0;
            __syncthreads();
            s[t] += tmp;
            __syncthreads();
        }
        if (i < n) row_ptr[i] = carry + s[t] - v;   // exclusive
        __syncthreads();
        if (t == 0) carry += s[1023];
        __syncthreads();
    }
    if (t == 0) row_ptr[n] = carry;
}

__global__ void k_fill(const int* __restrict__ src, const int* __restrict__ dst,
                       const int* __restrict__ row_ptr, int* __restrict__ cursor,
                       int* __restrict__ csr, int E) {
    int i = blockIdx.x * 256 + threadIdx.x;
    if (i < E) {
        int d = dst[i];
        int p = atomicAdd(&cursor[d], 1);
        csr[row_ptr[d] + p] = src[i];
    }
}

// ---------------- mean aggregation: one wave per node, fp64 accumulate ----------------
template<int D>
__global__ void k_aggr(const float* __restrict__ xin, const int* __restrict__ row_ptr,
                       const int* __restrict__ csr, float* __restrict__ agg, int n) {
    int wid = (blockIdx.x * blockDim.x + threadIdx.x) >> 6;
    int lane = threadIdx.x & 63;
    if (wid >= n) return;
    constexpr int V = D / 64;
    double acc[V];
#pragma unroll
    for (int i = 0; i < V; ++i) acc[i] = 0.0;
    int s0 = row_ptr[wid], s1 = row_ptr[wid + 1];
    for (int j = s0; j < s1; ++j) {
        int s = csr[j];
        const float* p = xin + (size_t)s * D + lane;
#pragma unroll
        for (int i = 0; i < V; ++i) acc[i] += (double)p[i * 64];
    }
    double inv = 1.0 / (double)max(s1 - s0, 1);
#pragma unroll
    for (int i = 0; i < V; ++i) agg[(size_t)wid * D + i * 64 + lane] = (float)(acc[i] * inv);
}

// ---------------- gate ----------------
template<int D>
__global__ void k_gate(const float* __restrict__ agg, const float* __restrict__ wg,
                       const float* __restrict__ bg, int* __restrict__ idx,
                       int* __restrict__ ecnt, float* __restrict__ gsum, int n) {
    __shared__ float swg[D * 8];
    __shared__ int hcnt[8];
    __shared__ float red[256];
    int t = threadIdx.x;
    if (t < 8) hcnt[t] = 0;
    for (int i = t; i < D * 8; i += 256) swg[i] = wg[i];
    __syncthreads();
    int nid = blockIdx.x * 256 + t;
    float stdv = 0.f;
    if (nid < n) {
        double lg[8];
#pragma unroll
        for (int e = 0; e < 8; ++e) lg[e] = (double)bg[e];
        const float* ap = agg + (size_t)nid * D;
        for (int k = 0; k < D; k += 4) {
            float4 a = *(const float4*)(ap + k);
#pragma unroll
            for (int e = 0; e < 8; ++e) {
                lg[e] += (double)a.x * swg[(k + 0) * 8 + e] + (double)a.y * swg[(k + 1) * 8 + e]
                       + (double)a.z * swg[(k + 2) * 8 + e] + (double)a.w * swg[(k + 3) * 8 + e];
            }
        }
        double m = lg[0];
        int am = 0;
#pragma unroll
        for (int e = 1; e < 8; ++e) if (lg[e] > m) { m = lg[e]; am = e; }
        double s = 0.0, p[8];
#pragma unroll
        for (int e = 0; e < 8; ++e) { p[e] = exp(lg[e] - m); s += p[e]; }
        double invs = 1.0 / s, sq = 0.0;
#pragma unroll
        for (int e = 0; e < 8; ++e) { double q = p[e] * invs; sq += q * q; }
        stdv = (float)sqrt(fmax(sq - 0.125, 0.0) / 7.0);
        idx[nid] = am;
        atomicAdd(&hcnt[am], 1);
    }
    red[t] = stdv;
    __syncthreads();
    for (int off = 128; off > 0; off >>= 1) {
        if (t < off) red[t] += red[t + off];
        __syncthreads();
    }
    if (t == 0) atomicAdd(gsum, red[0]);
    if (t < 8 && hcnt[t] > 0) atomicAdd(&ecnt[t], hcnt[t]);
}

__global__ void k_offsets(const int* __restrict__ ecnt, int* __restrict__ eoff) {
    if (threadIdx.x == 0 && blockIdx.x == 0) {
        int s = 0;
        for (int e = 0; e < 8; ++e) { eoff[e] = s; s += ecnt[e]; }
        eoff[8] = s;
    }
}

__global__ void k_perm(const int* __restrict__ idx, const int* __restrict__ eoff,
                       int* __restrict__ ecur, int* __restrict__ perm, int n) {
    __shared__ int lcnt[8], lbase[8];
    int t = threadIdx.x;
    if (t < 8) lcnt[t] = 0;
    __syncthreads();
    int nid = blockIdx.x * 256 + t;
    int e = 0, r = 0;
    bool valid = (nid < n);
    if (valid) { e = idx[nid]; r = atomicAdd(&lcnt[e], 1); }
    __syncthreads();
    if (t < 8) lbase[t] = lcnt[t] ? atomicAdd(&ecur[t], lcnt[t]) : 0;
    __syncthreads();
    if (valid) perm[eoff[e] + lbase[e] + r] = nid;
}

// ---------------- VALU fp32 GEMM (round-2 verbatim; bit-identical h1) ----------------
template<int DIN, int NCOL, bool EXPERT, bool RELU>
__global__ __launch_bounds__(256) void k_gemm_f32(
    const float* __restrict__ agg, const float* __restrict__ a2,
    const float* __restrict__ B1, const float* __restrict__ B2,
    const float* __restrict__ bias,
    const int* __restrict__ perm, const int* __restrict__ eoff,
    float* __restrict__ outp, int n) {
    constexpr int CT = NCOL / 4;
    constexpr int RG = 256 / CT;
    constexpr int RPT = 64 / RG;
    __shared__ float a_tile[64 * 64];
    __shared__ int rows[64];
    int t = threadIdx.x;
    int e = 0, base = 0, cnt = n;
    if (EXPERT) { e = blockIdx.y; base = eoff[e]; cnt = eoff[e + 1] - base; }
    int rs = blockIdx.x * 64;
    if (rs >= cnt) return;
    int nrows = min(64, cnt - rs);
    if (t < 64) {
        int j = rs + min(t, nrows - 1);
        rows[t] = EXPERT ? perm[base + j] : j;
    }
    __syncthreads();
    int cg = t % CT, rg = t / CT;
    int cols = cg * 4;
    int sr = t >> 2;
    int sk = (t & 3) * 16;
    int grow = rows[sr];
    const float* B1e = B1 + (EXPERT ? (size_t)e * DIN * NCOL : 0);
    float acc[RPT][4];
#pragma unroll
    for (int r = 0; r < RPT; ++r) { acc[r][0] = 0.f; acc[r][1] = 0.f; acc[r][2] = 0.f; acc[r][3] = 0.f; }

#pragma unroll
    for (int half = 0; half < 2; ++half) {
        const float* B = half ? B2 : B1e;
        const float* Af = half ? a2 : agg;
        for (int kc = 0; kc < DIN; kc += 64) {
            __syncthreads();
            {
                const float4* p = (const float4*)(Af + (size_t)grow * DIN + kc + sk);
                float4* d4 = (float4*)&a_tile[sr * 64 + sk];
                d4[0] = p[0]; d4[1] = p[1]; d4[2] = p[2]; d4[3] = p[3];
            }
            __syncthreads();
            const float* Bp = B + (size_t)kc * NCOL + cols;
            for (int k = 0; k < 64; k += 4) {
                float bx[4][4];
#pragma unroll
                for (int kk = 0; kk < 4; ++kk) {
                    float4 br = *(const float4*)(Bp + (size_t)(k + kk) * NCOL);
                    bx[kk][0] = br.x; bx[kk][1] = br.y; bx[kk][2] = br.z; bx[kk][3] = br.w;
                }
#pragma unroll
                for (int r = 0; r < RPT; ++r) {
                    float4 a = *(const float4*)&a_tile[(rg * RPT + r) * 64 + k];
#pragma unroll
                    for (int c = 0; c < 4; ++c) {
                        acc[r][c] = fmaf(a.x, bx[0][c], acc[r][c]);
                        acc[r][c] = fmaf(a.y, bx[1][c], acc[r][c]);
                        acc[r][c] = fmaf(a.z, bx[2][c], acc[r][c]);
                        acc[r][c] = fmaf(a.w, bx[3][c], acc[r][c]);
                    }
                }
            }
        }
    }
    float4 bb = *(const float4*)(bias + (EXPERT ? e * NCOL : 0) + cols);
#pragma unroll
    for (int r = 0; r < RPT; ++r) {
        int rr = rg * RPT + r;
        if (rr < nrows) {
            int gr = rows[rr];
            float v0 = acc[r][0] + bb.x, v1 = acc[r][1] + bb.y;
            float v2 = acc[r][2] + bb.z, v3 = acc[r][3] + bb.w;
            if (RELU) { v0 = fmaxf(v0, 0.f); v1 = fmaxf(v1, 0.f); v2 = fmaxf(v2, 0.f); v3 = fmaxf(v3, 0.f); }
            *(float4*)(outp + (size_t)gr * NCOL + cols) = make_float4(v0, v1, v2, v3);
        }
    }
}

// ---------------- MFMA GEMM (layers 2/3; hi-only bf16 A) ----------------
template<int DIN, int MODE, int CT>
DEV void gemm_half(const float* __restrict__ Af, const unsigned short* __restrict__ BT,
                   short (*Ah)[40], short (*Al)[40], short (*Bs)[40],
                   const int* rows, f32x4 (&acc)[4][CT], int t, int lane, int w) {
    int q = lane >> 4, m16 = lane & 15;
    int r = t >> 2, part = t & 3;
    for (int kc = 0; kc < DIN; kc += 32) {
        __syncthreads();
        {
            const float* pf = Af + (size_t)rows[r] * DIN + kc + part * 8;
            float4 p0 = *(const float4*)pf, p1 = *(const float4*)(pf + 4);
            float va[8] = { p0.x, p0.y, p0.z, p0.w, p1.x, p1.y, p1.z, p1.w };
            short8 h, l;
#pragma unroll
            for (int j = 0; j < 8; ++j) {
                unsigned short hb = f2bf(va[j]);
                h[j] = (short)hb;
                l[j] = (short)((MODE == 1) ? f2bf(va[j] - bf2f(hb)) : 0);
            }
            *(short8*)&Ah[r][part * 8] = h;
            if (MODE == 1) *(short8*)&Al[r][part * 8] = l;
        }
#pragma unroll
        for (int j = 0; j < CT; ++j) {
            int c = t + 256 * j;
            int nn = c >> 2, pp = c & 3;
            *(uint4*)&Bs[nn][pp * 8] = *(const uint4*)(BT + (size_t)nn * DIN + kc + pp * 8);
        }
        __syncthreads();
        short8 af[4], alf[4], bf[CT];
#pragma unroll
        for (int rt = 0; rt < 4; ++rt) {
            af[rt] = *(short8*)&Ah[rt * 16 + m16][q * 8];
            if (MODE == 1) alf[rt] = *(short8*)&Al[rt * 16 + m16][q * 8];
        }
#pragma unroll
        for (int ct = 0; ct < CT; ++ct) bf[ct] = *(short8*)&Bs[w * CT * 16 + ct * 16 + m16][q * 8];
#pragma unroll
        for (int rt = 0; rt < 4; ++rt)
#pragma unroll
            for (int ct = 0; ct < CT; ++ct) {
                acc[rt][ct] = __builtin_amdgcn_mfma_f32_16x16x32_bf16(af[rt], bf[ct], acc[rt][ct], 0, 0, 0);
                if (MODE == 1)
                    acc[rt][ct] = __builtin_amdgcn_mfma_f32_16x16x32_bf16(alf[rt], bf[ct], acc[rt][ct], 0, 0, 0);
            }
    }
}

template<int DIN, int M0, int M1, int CT, bool EXPERT, bool RELU>
__global__ __launch_bounds__(256) void k_gemm(
    const float* __restrict__ agg, const float* __restrict__ a2,
    const unsigned short* __restrict__ B0T, const unsigned short* __restrict__ B1T,
    const unsigned short* __restrict__ bias,
    const int* __restrict__ perm, const int* __restrict__ eoff,
    void* __restrict__ outp, const int* __restrict__ outflags, int n) {
    constexpr int NCOL = CT * 64;
    constexpr bool NEEDLO = (M0 == 1) || (M1 == 1);
    __shared__ short Ah[64][40];
    __shared__ short Al[NEEDLO ? 64 : 1][40];
    __shared__ short Bs[NCOL][40];
    __shared__ int rows[64];
    int t = threadIdx.x;
    int lane = t & 63, w = t >> 6;
    int e = 0, base = 0, cnt = n;
    if (EXPERT) { e = blockIdx.y; base = eoff[e]; cnt = eoff[e + 1] - base; }
    int rs = blockIdx.x * 64;
    if (rs >= cnt) return;
    int nrows = min(64, cnt - rs);
    if (t < 64) {
        int j = rs + min(t, nrows - 1);
        rows[t] = EXPERT ? perm[base + j] : j;
    }
    __syncthreads();
    f32x4 acc[4][CT];
#pragma unroll
    for (int rt = 0; rt < 4; ++rt)
#pragma unroll
        for (int ct = 0; ct < CT; ++ct) acc[rt][ct] = (f32x4)(0.f);

    gemm_half<DIN, M0, CT>(agg, B0T + (EXPERT ? (size_t)e * DIN * NCOL : 0),
                           Ah, Al, Bs, rows, acc, t, lane, w);
    gemm_half<DIN, M1, CT>(a2, B1T, Ah, Al, Bs, rows, acc, t, lane, w);

    int q = lane >> 4, m16 = lane & 15;
    bool obf = (outflags != nullptr) && (outflags[0] != 0);
#pragma unroll
    for (int ct = 0; ct < CT; ++ct) {
        int col = w * CT * 16 + ct * 16 + m16;
        float bv = bf2f(bias[(EXPERT ? e * NCOL : 0) + col]);
#pragma unroll
        for (int rt = 0; rt < 4; ++rt)
#pragma unroll
            for (int i = 0; i < 4; ++i) {
                int rr = rt * 16 + q * 4 + i;
                if (rr < nrows) {
                    int gr = rows[rr];
                    float v = acc[rt][ct][i] + bv;
                    if (RELU) v = fmaxf(v, 0.f);
                    if (outflags == nullptr)
                        ((float*)outp)[(size_t)gr * NCOL + col] = v;
                    else if (obf)
                        ((unsigned short*)outp)[(size_t)gr * NCOL + col] = f2bf(v);
                    else
                        ((float*)outp)[(size_t)gr * NCOL + col] = v;
                }
            }
    }
}

__global__ void k_final(const float* __restrict__ gsum, void* __restrict__ outp,
                        const int* __restrict__ flags) {
    if (threadIdx.x == 0 && blockIdx.x == 0) {
        float g = (gsum[0] + gsum[1]) * (0.5f / 50000.0f);
        if (flags[0]) ((unsigned short*)outp)[(size_t)50000 * 128] = f2bf(g);
        else          ((float*)outp)[(size_t)50000 * 128] = g;
    }
}

extern "C" void kernel_launch(void* const* d_in, const int* in_sizes, int n_in,
                              void* d_out, int out_size, void* d_ws, size_t ws_size,
                              hipStream_t stream) {
    constexpr int N = 50000, E = 800000;
    const int* ei = (const int*)d_in[1];

    // ---- workspace layout ----
    int* ip = (int*)d_ws;
    int* deg = ip;            ip += N;
    int* cursor = ip;         ip += N;
    int* ecnt = ip;           ip += 16;
    int* ecur = ip;           ip += 16;
    float* gsum = (float*)ip; ip += 2;
    int* flags = ip;          ip += 2;
    int* row_ptr = ip;        ip += N + 1;
    int* csr = ip;            ip += E;
    int* idxb = ip;           ip += N;
    int* permb = ip;          ip += N;
    int* eoff = ip;           ip += 18;
    int* src32 = ip;          ip += E;
    int* dst32 = ip;          ip += E;
    size_t off = (size_t)((char*)ip - (char*)d_ws);
    off = (off + 255) & ~(size_t)255;
    float* fp = (float*)((char*)d_ws + off);
    float* xf   = fp; fp += (size_t)N * 128;
    float* wg1f = fp; fp += 128 * 8;
    float* bg1f = fp; fp += 8;
    float* wg2f = fp; fp += 256 * 8;
    float* bg2f = fp; fp += 8;
    float* we1f = fp; fp += 8 * 128 * 256;   // fp32 weights for layer-1 VALU GEMM
    float* wr1f = fp; fp += 128 * 256;
    float* be1f = fp; fp += 8 * 256;
    float* agg = fp; fp += (size_t)N * 256;
    float* h1  = fp; fp += (size_t)N * 256;
    float* h2  = fp; fp += (size_t)N * 256;
    unsigned short* wp = (unsigned short*)fp;
    unsigned short* we2c = wp; wp += 8 * 256 * 256;   // bf16 canonical copies
    unsigned short* wr2c = wp; wp += 256 * 256;
    unsigned short* wl3c = wp; wp += 256 * 128;
    unsigned short* wr3c = wp; wp += 256 * 128;
    unsigned short* be2c = wp; wp += 8 * 256;
    unsigned short* bl3c = wp; wp += 128;
    unsigned short* we2T = wp; wp += 8 * 256 * 256;   // transposed [n][k]
    unsigned short* wr2T = wp; wp += 256 * 256;
    unsigned short* wl3T = wp; wp += 256 * 128;
    unsigned short* wr3T = wp; wp += 256 * 128;

    hipMemsetAsync(d_ws, 0, (size_t)(2 * N + 36) * 4, stream);

    // ---- dtype detection + conversions ----
    k_detect<<<1, 64, 0, stream>>>((const unsigned*)d_in[0], ei, flags);
    struct { const void* s; float* d; int n; } cv[8] = {
        { d_in[0],  xf,   N * 128 },
        { d_in[2],  wg1f, 128 * 8 },   { d_in[3],  bg1f, 8 },
        { d_in[7],  wg2f, 256 * 8 },   { d_in[8],  bg2f, 8 },
        { d_in[4],  we1f, 8 * 128 * 256 }, { d_in[6], wr1f, 128 * 256 },
        { d_in[5],  be1f, 8 * 256 },
    };
    for (int i = 0; i < 8; ++i)
        k_cvt<<<(cv[i].n + 255) / 256, 256, 0, stream>>>(cv[i].s, cv[i].d, cv[i].n, flags);
    struct { const void* s; unsigned short* d; int n; } cb[6] = {
        { d_in[9],  we2c, 8 * 256 * 256 }, { d_in[11], wr2c, 256 * 256 },
        { d_in[12], wl3c, 256 * 128 },     { d_in[14], wr3c, 256 * 128 },
        { d_in[10], be2c, 8 * 256 },       { d_in[13], bl3c, 128 },
    };
    for (int i = 0; i < 6; ++i)
        k_cvt_bf<<<(cb[i].n + 255) / 256, 256, 0, stream>>>(cb[i].s, cb[i].d, cb[i].n, flags);
    k_cvt_idx<<<(E + 255) / 256, 256, 0, stream>>>(ei, src32, dst32, E, flags);

    // ---- weight transposes to B^T [n][k] (layers 2/3 only) ----
    k_transpose<<<dim3(8, 8, 8), 256, 0, stream>>>(we2c, we2T, 256, 256);
    k_transpose<<<dim3(8, 8, 1), 256, 0, stream>>>(wr2c, wr2T, 256, 256);
    k_transpose<<<dim3(4, 8, 1), 256, 0, stream>>>(wl3c, wl3T, 256, 128);
    k_transpose<<<dim3(4, 8, 1), 256, 0, stream>>>(wr3c, wr3T, 256, 128);

    // ---- CSR ----
    constexpr int NB = (N + 255) / 256;
    k_degree<<<(E + 255) / 256, 256, 0, stream>>>(dst32, deg, E);
    k_scan<<<1, 1024, 0, stream>>>(deg, row_ptr, N);
    k_fill<<<(E + 255) / 256, 256, 0, stream>>>(src32, dst32, row_ptr, cursor, csr, E);

    constexpr int GB = (N + 63) / 64;
    // ---- layer 1: 128 -> 256, MoE + root(x), relu — VALU fp32 (bit-identical to round-2 h1) ----
    k_aggr<128><<<(N + 3) / 4, 256, 0, stream>>>(xf, row_ptr, csr, agg, N);
    k_gate<128><<<NB, 256, 0, stream>>>(agg, wg1f, bg1f, idxb, ecnt, gsum, N);
    k_offsets<<<1, 1, 0, stream>>>(ecnt, eoff);
    k_perm<<<NB, 256, 0, stream>>>(idxb, eoff, ecur, permb, N);
    k_gemm_f32<128, 256, true, true><<<dim3(GB, 8), 256, 0, stream>>>(
        agg, xf, we1f, wr1f, be1f, permb, eoff, h1, N);

    // ---- layer 2: 256 -> 256, MoE + root(h1), relu — MFMA hi-only ----
    k_aggr<256><<<(N + 3) / 4, 256, 0, stream>>>(h1, row_ptr, csr, agg, N);
    k_gate<256><<<NB, 256, 0, stream>>>(agg, wg2f, bg2f, idxb, ecnt + 8, gsum + 1, N);
    k_offsets<<<1, 1, 0, stream>>>(ecnt + 8, eoff + 9);
    k_perm<<<NB, 256, 0, stream>>>(idxb, eoff + 9, ecur + 8, permb, N);
    k_gemm<256, 0, 0, 4, true, true><<<dim3(GB, 8), 256, 0, stream>>>(
        agg, h1, we2T, wr2T, be2c, permb, eoff + 9, h2, nullptr, N);

    // ---- layer 3: plain SAGE 256 -> 128 — MFMA hi-only ----
    k_aggr<256><<<(N + 3) / 4, 256, 0, stream>>>(h2, row_ptr, csr, agg, N);
    k_gemm<256, 0, 0, 2, false, false><<<dim3(GB, 1), 256, 0, stream>>>(
        agg, h2, wl3T, wr3T, bl3c, nullptr, nullptr, d_out, flags, N);

    k_final<<<1, 1, 0, stream>>>(gsum, d_out, flags);
}

// Round 9
// 813.876 us; speedup vs baseline: 1.3771x; 1.1168x over previous
//
#include <hip/hip_runtime.h>
#include <hip/hip_bf16.h>
#include <stdint.h>

#define DEV static __device__ __forceinline__

typedef __attribute__((ext_vector_type(8))) short short8;   // 8 bf16 (4 VGPRs)
typedef __attribute__((ext_vector_type(4))) float f32x4;    // MFMA accumulator

DEV float bf2f(unsigned short u) { return __uint_as_float(((unsigned)u) << 16); }
DEV float bflo(unsigned u) { return __uint_as_float(u << 16); }
DEV float bfhi(unsigned u) { return __uint_as_float(u & 0xffff0000u); }
DEV unsigned short f2bf(float f) {
    unsigned u = __float_as_uint(f);
    u += 0x7fff + ((u >> 16) & 1);   // RNE
    return (unsigned short)(u >> 16);
}

// ---------------- edge_index width detection (int64 vs int32) ----------------
__global__ void k_detect(const int* __restrict__ ei, int* __restrict__ flags) {
    if (threadIdx.x == 0 && blockIdx.x == 0) {
        int zeros = 0;
        for (int i = 0; i < 128; ++i) if (ei[2 * i + 1] == 0) ++zeros;
        flags[1] = (zeros >= 64) ? 1 : 0;
    }
}

__global__ void k_cvt_idx(const int* __restrict__ ei, int* __restrict__ src32,
                          int* __restrict__ dst32, int E, const int* __restrict__ flags) {
    int i = blockIdx.x * 256 + threadIdx.x;
    if (i >= E) return;
    if (flags[1]) { src32[i] = ei[2 * i]; dst32[i] = ei[2 * E + 2 * i]; }
    else          { src32[i] = ei[i];     dst32[i] = ei[E + i]; }
}

// ---------------- fused transpose+narrow: fp32 in[r][c] -> bf16 out[c][r] ----------------
__global__ void k_transpose_nb(const float* __restrict__ in, unsigned short* __restrict__ out,
                               int R, int C) {
    __shared__ unsigned short tile[32][33];
    int tx = threadIdx.x & 31, ty = threadIdx.x >> 5;   // 256 threads = 32x8
    size_t mat = (size_t)blockIdx.z * R * C;
    int r0 = blockIdx.y * 32, c0 = blockIdx.x * 32;
#pragma unroll
    for (int j = 0; j < 32; j += 8)
        tile[ty + j][tx] = f2bf(in[mat + (size_t)(r0 + ty + j) * C + c0 + tx]);
    __syncthreads();
#pragma unroll
    for (int j = 0; j < 32; j += 8)
        out[mat + (size_t)(c0 + ty + j) * R + r0 + tx] = tile[tx][ty + j];
}

// ---------------- CSR build (round-5 verbatim) ----------------
__global__ void k_degree(const int* __restrict__ dst, int* __restrict__ deg, int E) {
    int i = blockIdx.x * 256 + threadIdx.x;
    if (i < E) atomicAdd(&deg[dst[i]], 1);
}

__global__ void k_scan(const int* __restrict__ deg, int* __restrict__ row_ptr, int n) {
    __shared__ int s[1024];
    __shared__ int carry;
    int t = threadIdx.x;
    if (t == 0) carry = 0;
    __syncthreads();
    for (int base = 0; base < n; base += 1024) {
        int i = base + t;
        int v = (i < n) ? deg[i] : 0;
        s[t] = v;
        __syncthreads();
        for (int off = 1; off < 1024; off <<= 1) {
            int tmp = (t >= off) ? s[t - off] : 0;
            __syncthreads();
            s[t] += tmp;
            __syncthreads();
        }
        if (i < n) row_ptr[i] = carry + s[t] - v;   // exclusive
        __syncthreads();
        if (t == 0) carry += s[1023];
        __syncthreads();
    }
    if (t == 0) row_ptr[n] = carry;
}

__global__ void k_fill(const int* __restrict__ src, const int* __restrict__ dst,
                       const int* __restrict__ row_ptr, int* __restrict__ cursor,
                       int* __restrict__ csr, int E) {
    int i = blockIdx.x * 256 + threadIdx.x;
    if (i < E) {
        int d = dst[i];
        int p = atomicAdd(&cursor[d], 1);
        csr[row_ptr[d] + p] = src[i];
    }
}

// ---------------- mean aggregation: one wave/node, fp64 accumulate, fp32 source ----------------
// Vectorized: lane owns contiguous columns lane*V..lane*V+V-1. Per-element add sequence
// (j ascending) identical to the round-5 strided version -> agg bit-identical (gate-safe).
template<int D>
__global__ void k_aggr(const float* __restrict__ xin, const int* __restrict__ row_ptr,
                       const int* __restrict__ csr, float* __restrict__ agg, int n) {
    int wid = (blockIdx.x * blockDim.x + threadIdx.x) >> 6;
    int lane = threadIdx.x & 63;
    if (wid >= n) return;
    constexpr int V = D / 64;
    double acc[V];
#pragma unroll
    for (int i = 0; i < V; ++i) acc[i] = 0.0;
    int s0 = row_ptr[wid], s1 = row_ptr[wid + 1];
    for (int j = s0; j < s1; ++j) {
        const float* p = xin + (size_t)csr[j] * D + lane * V;
        if (V == 2) {
            float2 f = *(const float2*)p;
            acc[0] += (double)f.x; acc[1] += (double)f.y;
        } else {
            float4 f = *(const float4*)p;
            acc[0] += (double)f.x; acc[1] += (double)f.y;
            acc[2] += (double)f.z; acc[3] += (double)f.w;
        }
    }
    double inv = 1.0 / (double)max(s1 - s0, 1);
#pragma unroll
    for (int i = 0; i < V; ++i)
        agg[(size_t)wid * D + lane * V + i] = (float)(acc[i] * inv);
}

// bf16-source variant (gate-free consumers only)
template<int D>
__global__ void k_aggr_bf(const unsigned short* __restrict__ xin, const int* __restrict__ row_ptr,
                          const int* __restrict__ csr, float* __restrict__ agg, int n) {
    int wid = (blockIdx.x * blockDim.x + threadIdx.x) >> 6;
    int lane = threadIdx.x & 63;
    if (wid >= n) return;
    constexpr int V = D / 64;
    double acc[V];
#pragma unroll
    for (int i = 0; i < V; ++i) acc[i] = 0.0;
    int s0 = row_ptr[wid], s1 = row_ptr[wid + 1];
    for (int j = s0; j < s1; ++j) {
        const unsigned short* p = xin + (size_t)csr[j] * D + lane * V;
        if (V == 2) {
            unsigned u = *(const unsigned*)p;
            acc[0] += (double)bflo(u); acc[1] += (double)bfhi(u);
        } else {
            uint2 u = *(const uint2*)p;
            acc[0] += (double)bflo(u.x); acc[1] += (double)bfhi(u.x);
            acc[2] += (double)bflo(u.y); acc[3] += (double)bfhi(u.y);
        }
    }
    double inv = 1.0 / (double)max(s1 - s0, 1);
#pragma unroll
    for (int i = 0; i < V; ++i)
        agg[(size_t)wid * D + lane * V + i] = (float)(acc[i] * inv);
}

// ---------------- gate (round-5 verbatim; fp32 weights read directly) ----------------
template<int D>
__global__ void k_gate(const float* __restrict__ agg, const float* __restrict__ wg,
                       const float* __restrict__ bg, int* __restrict__ idx,
                       int* __restrict__ ecnt, float* __restrict__ gsum, int n) {
    __shared__ float swg[D * 8];
    __shared__ int hcnt[8];
    __shared__ float red[256];
    int t = threadIdx.x;
    if (t < 8) hcnt[t] = 0;
    for (int i = t; i < D * 8; i += 256) swg[i] = wg[i];
    __syncthreads();
    int nid = blockIdx.x * 256 + t;
    float stdv = 0.f;
    if (nid < n) {
        double lg[8];
#pragma unroll
        for (int e = 0; e < 8; ++e) lg[e] = (double)bg[e];
        const float* ap = agg + (size_t)nid * D;
        for (int k = 0; k < D; k += 4) {
            float4 a = *(const float4*)(ap + k);
#pragma unroll
            for (int e = 0; e < 8; ++e) {
                lg[e] += (double)a.x * swg[(k + 0) * 8 + e] + (double)a.y * swg[(k + 1) * 8 + e]
                       + (double)a.z * swg[(k + 2) * 8 + e] + (double)a.w * swg[(k + 3) * 8 + e];
            }
        }
        double m = lg[0];
        int am = 0;
#pragma unroll
        for (int e = 1; e < 8; ++e) if (lg[e] > m) { m = lg[e]; am = e; }
        double s = 0.0, p[8];
#pragma unroll
        for (int e = 0; e < 8; ++e) { p[e] = exp(lg[e] - m); s += p[e]; }
        double invs = 1.0 / s, sq = 0.0;
#pragma unroll
        for (int e = 0; e < 8; ++e) { double q = p[e] * invs; sq += q * q; }
        stdv = (float)sqrt(fmax(sq - 0.125, 0.0) / 7.0);
        idx[nid] = am;
        atomicAdd(&hcnt[am], 1);
    }
    red[t] = stdv;
    __syncthreads();
    for (int off = 128; off > 0; off >>= 1) {
        if (t < off) red[t] += red[t + off];
        __syncthreads();
    }
    if (t == 0) atomicAdd(gsum, red[0]);
    if (t < 8 && hcnt[t] > 0) atomicAdd(&ecnt[t], hcnt[t]);
}

__global__ void k_offsets(const int* __restrict__ ecnt, int* __restrict__ eoff) {
    if (threadIdx.x == 0 && blockIdx.x == 0) {
        int s = 0;
        for (int e = 0; e < 8; ++e) { eoff[e] = s; s += ecnt[e]; }
        eoff[8] = s;
    }
}

__global__ void k_perm(const int* __restrict__ idx, const int* __restrict__ eoff,
                       int* __restrict__ ecur, int* __restrict__ perm, int n) {
    __shared__ int lcnt[8], lbase[8];
    int t = threadIdx.x;
    if (t < 8) lcnt[t] = 0;
    __syncthreads();
    int nid = blockIdx.x * 256 + t;
    int e = 0, r = 0;
    bool valid = (nid < n);
    if (valid) { e = idx[nid]; r = atomicAdd(&lcnt[e], 1); }
    __syncthreads();
    if (t < 8) lbase[t] = lcnt[t] ? atomicAdd(&ecur[t], lcnt[t]) : 0;
    __syncthreads();
    if (valid) perm[eoff[e] + lbase[e] + r] = nid;
}

// ---------------- VALU fp32 GEMM, layer 1 (round-5 verbatim; h1 bit-identical) ----------------
template<int DIN, int NCOL, bool EXPERT, bool RELU>
__global__ __launch_bounds__(256) void k_gemm_f32(
    const float* __restrict__ agg, const float* __restrict__ a2,
    const float* __restrict__ B1, const float* __restrict__ B2,
    const float* __restrict__ bias,
    const int* __restrict__ perm, const int* __restrict__ eoff,
    float* __restrict__ outp, int n) {
    constexpr int CT = NCOL / 4;
    constexpr int RG = 256 / CT;
    constexpr int RPT = 64 / RG;
    __shared__ float a_tile[64 * 64];
    __shared__ int rows[64];
    int t = threadIdx.x;
    int e = 0, base = 0, cnt = n;
    if (EXPERT) { e = blockIdx.y; base = eoff[e]; cnt = eoff[e + 1] - base; }
    int rs = blockIdx.x * 64;
    if (rs >= cnt) return;
    int nrows = min(64, cnt - rs);
    if (t < 64) {
        int j = rs + min(t, nrows - 1);
        rows[t] = EXPERT ? perm[base + j] : j;
    }
    __syncthreads();
    int cg = t % CT, rg = t / CT;
    int cols = cg * 4;
    int sr = t >> 2;
    int sk = (t & 3) * 16;
    int grow = rows[sr];
    const float* B1e = B1 + (EXPERT ? (size_t)e * DIN * NCOL : 0);
    float acc[RPT][4];
#pragma unroll
    for (int r = 0; r < RPT; ++r) { acc[r][0] = 0.f; acc[r][1] = 0.f; acc[r][2] = 0.f; acc[r][3] = 0.f; }

#pragma unroll
    for (int half = 0; half < 2; ++half) {
        const float* B = half ? B2 : B1e;
        const float* Af = half ? a2 : agg;
        for (int kc = 0; kc < DIN; kc += 64) {
            __syncthreads();
            {
                const float4* p = (const float4*)(Af + (size_t)grow * DIN + kc + sk);
                float4* d4 = (float4*)&a_tile[sr * 64 + sk];
                d4[0] = p[0]; d4[1] = p[1]; d4[2] = p[2]; d4[3] = p[3];
            }
            __syncthreads();
            const float* Bp = B + (size_t)kc * NCOL + cols;
            for (int k = 0; k < 64; k += 4) {
                float bx[4][4];
#pragma unroll
                for (int kk = 0; kk < 4; ++kk) {
                    float4 br = *(const float4*)(Bp + (size_t)(k + kk) * NCOL);
                    bx[kk][0] = br.x; bx[kk][1] = br.y; bx[kk][2] = br.z; bx[kk][3] = br.w;
                }
#pragma unroll
                for (int r = 0; r < RPT; ++r) {
                    float4 a = *(const float4*)&a_tile[(rg * RPT + r) * 64 + k];
#pragma unroll
                    for (int c = 0; c < 4; ++c) {
                        acc[r][c] = fmaf(a.x, bx[0][c], acc[r][c]);
                        acc[r][c] = fmaf(a.y, bx[1][c], acc[r][c]);
                        acc[r][c] = fmaf(a.z, bx[2][c], acc[r][c]);
                        acc[r][c] = fmaf(a.w, bx[3][c], acc[r][c]);
                    }
                }
            }
        }
    }
    float4 bb = *(const float4*)(bias + (EXPERT ? e * NCOL : 0) + cols);
#pragma unroll
    for (int r = 0; r < RPT; ++r) {
        int rr = rg * RPT + r;
        if (rr < nrows) {
            int gr = rows[rr];
            float v0 = acc[r][0] + bb.x, v1 = acc[r][1] + bb.y;
            float v2 = acc[r][2] + bb.z, v3 = acc[r][3] + bb.w;
            if (RELU) { v0 = fmaxf(v0, 0.f); v1 = fmaxf(v1, 0.f); v2 = fmaxf(v2, 0.f); v3 = fmaxf(v3, 0.f); }
            *(float4*)(outp + (size_t)gr * NCOL + cols) = make_float4(v0, v1, v2, v3);
        }
    }
}

// ---------------- MFMA GEMM (layers 2/3). MODE 0: fp32 A -> f2bf in LDS (r5-proven).
// MODE 2: A already bf16, direct stage (same element mapping, same bits).
template<int DIN, int MODE, int CT>
DEV void gemm_half(const void* __restrict__ Asrc, const unsigned short* __restrict__ BT,
                   short (*Ah)[40], short (*Bs)[40],
                   const int* rows, f32x4 (&acc)[4][CT], int t, int lane, int w) {
    int q = lane >> 4, m16 = lane & 15;
    int r = t >> 2, part = t & 3;
    for (int kc = 0; kc < DIN; kc += 32) {
        __syncthreads();
        if (MODE == 2) {
            *(uint4*)&Ah[r][part * 8] =
                *(const uint4*)((const unsigned short*)Asrc + (size_t)rows[r] * DIN + kc + part * 8);
        } else {
            const float* pf = (const float*)Asrc + (size_t)rows[r] * DIN + kc + part * 8;
            float4 p0 = *(const float4*)pf, p1 = *(const float4*)(pf + 4);
            float va[8] = { p0.x, p0.y, p0.z, p0.w, p1.x, p1.y, p1.z, p1.w };
            short8 h;
#pragma unroll
            for (int j = 0; j < 8; ++j) h[j] = (short)f2bf(va[j]);
            *(short8*)&Ah[r][part * 8] = h;
        }
#pragma unroll
        for (int j = 0; j < CT; ++j) {
            int c = t + 256 * j;
            int nn = c >> 2, pp = c & 3;
            *(uint4*)&Bs[nn][pp * 8] = *(const uint4*)(BT + (size_t)nn * DIN + kc + pp * 8);
        }
        __syncthreads();
        short8 af[4], bfr[CT];
#pragma unroll
        for (int rt = 0; rt < 4; ++rt) af[rt] = *(short8*)&Ah[rt * 16 + m16][q * 8];
#pragma unroll
        for (int ct = 0; ct < CT; ++ct) bfr[ct] = *(short8*)&Bs[w * CT * 16 + ct * 16 + m16][q * 8];
#pragma unroll
        for (int rt = 0; rt < 4; ++rt)
#pragma unroll
            for (int ct = 0; ct < CT; ++ct)
                acc[rt][ct] = __builtin_amdgcn_mfma_f32_16x16x32_bf16(af[rt], bfr[ct], acc[rt][ct], 0, 0, 0);
    }
}

// OUTBF=true -> bf16 store (intermediate h2b); false -> fp32 store (d_out is fp32!)
template<int DIN, int M0, int M1, int CT, bool EXPERT, bool RELU, bool OUTBF>
__global__ __launch_bounds__(256) void k_gemm(
    const void* __restrict__ A0, const void* __restrict__ A1,
    const unsigned short* __restrict__ B0T, const unsigned short* __restrict__ B1T,
    const float* __restrict__ bias,
    const int* __restrict__ perm, const int* __restrict__ eoff,
    void* __restrict__ outp, int n) {
    constexpr int NCOL = CT * 64;
    __shared__ short Ah[64][40];
    __shared__ short Bs[NCOL][40];
    __shared__ int rows[64];
    int t = threadIdx.x;
    int lane = t & 63, w = t >> 6;
    int e = 0, base = 0, cnt = n;
    if (EXPERT) { e = blockIdx.y; base = eoff[e]; cnt = eoff[e + 1] - base; }
    int rs = blockIdx.x * 64;
    if (rs >= cnt) return;
    int nrows = min(64, cnt - rs);
    if (t < 64) {
        int j = rs + min(t, nrows - 1);
        rows[t] = EXPERT ? perm[base + j] : j;
    }
    __syncthreads();
    f32x4 acc[4][CT];
#pragma unroll
    for (int rt = 0; rt < 4; ++rt)
#pragma unroll
        for (int ct = 0; ct < CT; ++ct) acc[rt][ct] = (f32x4)(0.f);

    gemm_half<DIN, M0, CT>(A0, B0T + (EXPERT ? (size_t)e * DIN * NCOL : 0), Ah, Bs, rows, acc, t, lane, w);
    gemm_half<DIN, M1, CT>(A1, B1T, Ah, Bs, rows, acc, t, lane, w);

    int q = lane >> 4, m16 = lane & 15;
#pragma unroll
    for (int ct = 0; ct < CT; ++ct) {
        int col = w * CT * 16 + ct * 16 + m16;
        float bv = bias[(EXPERT ? e * NCOL : 0) + col];
#pragma unroll
        for (int rt = 0; rt < 4; ++rt)
#pragma unroll
            for (int i = 0; i < 4; ++i) {
                int rr = rt * 16 + q * 4 + i;
                if (rr < nrows) {
                    int gr = rows[rr];
                    float v = acc[rt][ct][i] + bv;
                    if (RELU) v = fmaxf(v, 0.f);
                    if (OUTBF) ((unsigned short*)outp)[(size_t)gr * NCOL + col] = f2bf(v);
                    else       ((float*)outp)[(size_t)gr * NCOL + col] = v;
                }
            }
    }
}

__global__ void k_final(const float* __restrict__ gsum, float* __restrict__ outf) {
    if (threadIdx.x == 0 && blockIdx.x == 0) {
        float g = (gsum[0] + gsum[1]) * (0.5f / 50000.0f);
        outf[(size_t)50000 * 128] = g;   // output buffer is fp32
    }
}

extern "C" void kernel_launch(void* const* d_in, const int* in_sizes, int n_in,
                              void* d_out, int out_size, void* d_ws, size_t ws_size,
                              hipStream_t stream) {
    constexpr int N = 50000, E = 800000;
    const float* x   = (const float*)d_in[0];
    const int* ei    = (const int*)d_in[1];
    const float* wg1 = (const float*)d_in[2];
    const float* bg1 = (const float*)d_in[3];
    const float* we1 = (const float*)d_in[4];
    const float* be1 = (const float*)d_in[5];
    const float* wr1 = (const float*)d_in[6];
    const float* wg2 = (const float*)d_in[7];
    const float* bg2 = (const float*)d_in[8];
    const float* we2 = (const float*)d_in[9];
    const float* be2 = (const float*)d_in[10];
    const float* wr2 = (const float*)d_in[11];
    const float* wl3 = (const float*)d_in[12];
    const float* bl3 = (const float*)d_in[13];
    const float* wr3 = (const float*)d_in[14];

    // ---- workspace layout ----
    int* ip = (int*)d_ws;
    int* deg = ip;            ip += N;
    int* cursor = ip;         ip += N;
    int* ecnt = ip;           ip += 16;
    int* ecur = ip;           ip += 16;
    float* gsum = (float*)ip; ip += 2;
    int* flags = ip;          ip += 2;
    int* row_ptr = ip;        ip += N + 1;
    int* csr = ip;            ip += E;
    int* idxb = ip;           ip += N;
    int* permb = ip;          ip += N;
    int* eoff = ip;           ip += 18;
    int* src32 = ip;          ip += E;
    int* dst32 = ip;          ip += E;
    size_t off = (size_t)((char*)ip - (char*)d_ws);
    off = (off + 255) & ~(size_t)255;
    float* fp = (float*)((char*)d_ws + off);
    float* agg = fp; fp += (size_t)N * 256;            // fp32 agg (layers 1-3)
    float* h1  = fp; fp += (size_t)N * 256;            // fp32 h1 (gate-2 critical)
    unsigned short* wp = (unsigned short*)fp;
    unsigned short* h2b  = wp; wp += (size_t)N * 256;  // bf16 h2 (gate-free)
    unsigned short* we2T = wp; wp += 8 * 256 * 256;    // bf16 B^T [n][k]
    unsigned short* wr2T = wp; wp += 256 * 256;
    unsigned short* wl3T = wp; wp += 256 * 128;
    unsigned short* wr3T = wp; wp += 256 * 128;

    hipMemsetAsync(d_ws, 0, (size_t)(2 * N + 36) * 4, stream);

    k_detect<<<1, 64, 0, stream>>>(ei, flags);
    k_cvt_idx<<<(E + 255) / 256, 256, 0, stream>>>(ei, src32, dst32, E, flags);

    // fused transpose+narrow to bf16 B^T [n][k] (layers 2/3)
    k_transpose_nb<<<dim3(8, 8, 8), 256, 0, stream>>>(we2, we2T, 256, 256);
    k_transpose_nb<<<dim3(8, 8, 1), 256, 0, stream>>>(wr2, wr2T, 256, 256);
    k_transpose_nb<<<dim3(4, 8, 1), 256, 0, stream>>>(wl3, wl3T, 256, 128);
    k_transpose_nb<<<dim3(4, 8, 1), 256, 0, stream>>>(wr3, wr3T, 256, 128);

    // CSR
    constexpr int NB = (N + 255) / 256;
    constexpr int WB = (N + 3) / 4;
    k_degree<<<(E + 255) / 256, 256, 0, stream>>>(dst32, deg, E);
    k_scan<<<1, 1024, 0, stream>>>(deg, row_ptr, N);
    k_fill<<<(E + 255) / 256, 256, 0, stream>>>(src32, dst32, row_ptr, cursor, csr, E);

    constexpr int GB = (N + 63) / 64;
    // ---- layer 1: 128 -> 256, MoE + root(x), relu — VALU fp32 (h1 bit-identical to r5) ----
    k_aggr<128><<<WB, 256, 0, stream>>>(x, row_ptr, csr, agg, N);
    k_gate<128><<<NB, 256, 0, stream>>>(agg, wg1, bg1, idxb, ecnt, gsum, N);
    k_offsets<<<1, 1, 0, stream>>>(ecnt, eoff);
    k_perm<<<NB, 256, 0, stream>>>(idxb, eoff, ecur, permb, N);
    k_gemm_f32<128, 256, true, true><<<dim3(GB, 8), 256, 0, stream>>>(
        agg, x, we1, wr1, be1, permb, eoff, h1, N);

    // ---- layer 2: 256 -> 256, MoE + root(h1), relu — MFMA MODE 0; bf16 h2b out ----
    k_aggr<256><<<WB, 256, 0, stream>>>(h1, row_ptr, csr, agg, N);  // fp32 gather (gate feeds)
    k_gate<256><<<NB, 256, 0, stream>>>(agg, wg2, bg2, idxb, ecnt + 8, gsum + 1, N);
    k_offsets<<<1, 1, 0, stream>>>(ecnt + 8, eoff + 9);
    k_perm<<<NB, 256, 0, stream>>>(idxb, eoff + 9, ecur + 8, permb, N);
    k_gemm<256, 0, 0, 4, true, true, true><<<dim3(GB, 8), 256, 0, stream>>>(
        agg, h1, we2T, wr2T, be2, permb, eoff + 9, h2b, N);

    // ---- layer 3: plain SAGE 256 -> 128 — bf16 gather (no gate), MFMA; fp32 out ----
    k_aggr_bf<256><<<WB, 256, 0, stream>>>(h2b, row_ptr, csr, agg, N);
    k_gemm<256, 0, 2, 2, false, false, false><<<dim3(GB, 1), 256, 0, stream>>>(
        agg, h2b, wl3T, wr3T, bl3, nullptr, nullptr, d_out, N);

    k_final<<<1, 1, 0, stream>>>(gsum, (float*)d_out);
}

// Round 10
// 700.660 us; speedup vs baseline: 1.5996x; 1.1616x over previous
//
#include <hip/hip_runtime.h>
#include <hip/hip_bf16.h>
#include <stdint.h>

#define DEV static __device__ __forceinline__

typedef __attribute__((ext_vector_type(8))) short short8;   // 8 bf16 (4 VGPRs)
typedef __attribute__((ext_vector_type(4))) float f32x4;    // MFMA accumulator

DEV float bf2f(unsigned short u) { return __uint_as_float(((unsigned)u) << 16); }
DEV float bflo(unsigned u) { return __uint_as_float(u << 16); }
DEV float bfhi(unsigned u) { return __uint_as_float(u & 0xffff0000u); }
DEV unsigned short f2bf(float f) {
    unsigned u = __float_as_uint(f);
    u += 0x7fff + ((u >> 16) & 1);   // RNE
    return (unsigned short)(u >> 16);
}

// ---------------- edge_index width detection (int64 vs int32) ----------------
__global__ void k_detect(const int* __restrict__ ei, int* __restrict__ flags) {
    if (threadIdx.x == 0 && blockIdx.x == 0) {
        int zeros = 0;
        for (int i = 0; i < 128; ++i) if (ei[2 * i + 1] == 0) ++zeros;
        flags[1] = (zeros >= 64) ? 1 : 0;
    }
}

__global__ void k_cvt_idx(const int* __restrict__ ei, int* __restrict__ src32,
                          int* __restrict__ dst32, int E, const int* __restrict__ flags) {
    int i = blockIdx.x * 256 + threadIdx.x;
    if (i >= E) return;
    if (flags[1]) { src32[i] = ei[2 * i]; dst32[i] = ei[2 * E + 2 * i]; }
    else          { src32[i] = ei[i];     dst32[i] = ei[E + i]; }
}

// ---------------- fused transpose+narrow: fp32 in[r][c] -> bf16 out[c][r] ----------------
__global__ void k_transpose_nb(const float* __restrict__ in, unsigned short* __restrict__ out,
                               int R, int C) {
    __shared__ unsigned short tile[32][33];
    int tx = threadIdx.x & 31, ty = threadIdx.x >> 5;   // 256 threads = 32x8
    size_t mat = (size_t)blockIdx.z * R * C;
    int r0 = blockIdx.y * 32, c0 = blockIdx.x * 32;
#pragma unroll
    for (int j = 0; j < 32; j += 8)
        tile[ty + j][tx] = f2bf(in[mat + (size_t)(r0 + ty + j) * C + c0 + tx]);
    __syncthreads();
#pragma unroll
    for (int j = 0; j < 32; j += 8)
        out[mat + (size_t)(c0 + ty + j) * R + r0 + tx] = tile[tx][ty + j];
}

// ---------------- CSR build: degree -> 3-phase shfl scan -> fill ----------------
__global__ void k_degree(const int* __restrict__ dst, int* __restrict__ deg, int E) {
    int i = blockIdx.x * 256 + threadIdx.x;
    if (i < E) atomicAdd(&deg[dst[i]], 1);
}

__global__ void k_scan1(const int* __restrict__ deg, int* __restrict__ row_ptr,
                        int* __restrict__ part, int n) {
    __shared__ int wsum[4];
    int t = threadIdx.x, lane = t & 63, wv = t >> 6;
    int i = blockIdx.x * 256 + t;
    int v0 = (i < n) ? deg[i] : 0;
    int v = v0;
#pragma unroll
    for (int d = 1; d < 64; d <<= 1) { int u = __shfl_up(v, d); if (lane >= d) v += u; }
    if (lane == 63) wsum[wv] = v;
    __syncthreads();
    int add = 0;
    for (int w2 = 0; w2 < wv; ++w2) add += wsum[w2];
    v += add;
    if (i < n) row_ptr[i] = v - v0;            // block-local exclusive
    if (t == 255) part[blockIdx.x] = v;        // block total
}

__global__ void k_scan2(int* __restrict__ part, int P) {
    __shared__ int wsum[4];
    int t = threadIdx.x, lane = t & 63, wv = t >> 6;
    int v0 = (t < P) ? part[t] : 0;
    int v = v0;
#pragma unroll
    for (int d = 1; d < 64; d <<= 1) { int u = __shfl_up(v, d); if (lane >= d) v += u; }
    if (lane == 63) wsum[wv] = v;
    __syncthreads();
    int add = 0;
    for (int w2 = 0; w2 < wv; ++w2) add += wsum[w2];
    v += add;
    if (t < P) part[t] = v - v0;               // exclusive over partials
}

__global__ void k_scan3(int* __restrict__ row_ptr, const int* __restrict__ part, int n, int E) {
    int i = blockIdx.x * 256 + threadIdx.x;
    if (i < n) row_ptr[i] += part[blockIdx.x];
    if (i == 0) row_ptr[n] = E;
}

__global__ void k_fill(const int* __restrict__ src, const int* __restrict__ dst,
                       const int* __restrict__ row_ptr, int* __restrict__ cursor,
                       int* __restrict__ csr, int E) {
    int i = blockIdx.x * 256 + threadIdx.x;
    if (i < E) {
        int d = dst[i];
        int p = atomicAdd(&cursor[d], 1);
        csr[row_ptr[d] + p] = src[i];
    }
}

// ---------------- mean aggregation: one wave/node, fp64 accumulate, 4-row unroll ----------------
// fp64 reorder vs the serial version perturbs agg by ~1e-16 relative — far below the
// ~1e-6 gate argmax cliff (R4 vs R5 bracketing). 4 independent rows in flight -> 4x MLP.
template<int D>
__global__ void k_aggr(const float* __restrict__ xin, const int* __restrict__ row_ptr,
                       const int* __restrict__ csr, float* __restrict__ agg, int n) {
    int wid = (blockIdx.x * blockDim.x + threadIdx.x) >> 6;
    int lane = threadIdx.x & 63;
    if (wid >= n) return;
    constexpr int V = D / 64;
    double a0[V], a1[V], a2[V], a3[V];
#pragma unroll
    for (int i = 0; i < V; ++i) { a0[i] = 0.0; a1[i] = 0.0; a2[i] = 0.0; a3[i] = 0.0; }
    int s0 = row_ptr[wid], s1 = row_ptr[wid + 1];
    int j = s0;
    for (; j + 4 <= s1; j += 4) {
        int i0 = csr[j], i1 = csr[j + 1], i2 = csr[j + 2], i3 = csr[j + 3];
        const float* p0 = xin + (size_t)i0 * D + lane * V;
        const float* p1 = xin + (size_t)i1 * D + lane * V;
        const float* p2 = xin + (size_t)i2 * D + lane * V;
        const float* p3 = xin + (size_t)i3 * D + lane * V;
        if (V == 2) {
            float2 f0 = *(const float2*)p0, f1 = *(const float2*)p1;
            float2 f2 = *(const float2*)p2, f3 = *(const float2*)p3;
            a0[0] += (double)f0.x; a0[1] += (double)f0.y;
            a1[0] += (double)f1.x; a1[1] += (double)f1.y;
            a2[0] += (double)f2.x; a2[1] += (double)f2.y;
            a3[0] += (double)f3.x; a3[1] += (double)f3.y;
        } else {
            float4 f0 = *(const float4*)p0, f1 = *(const float4*)p1;
            float4 f2 = *(const float4*)p2, f3 = *(const float4*)p3;
            a0[0] += (double)f0.x; a0[1] += (double)f0.y; a0[2] += (double)f0.z; a0[3] += (double)f0.w;
            a1[0] += (double)f1.x; a1[1] += (double)f1.y; a1[2] += (double)f1.z; a1[3] += (double)f1.w;
            a2[0] += (double)f2.x; a2[1] += (double)f2.y; a2[2] += (double)f2.z; a2[3] += (double)f2.w;
            a3[0] += (double)f3.x; a3[1] += (double)f3.y; a3[2] += (double)f3.z; a3[3] += (double)f3.w;
        }
    }
    for (; j < s1; ++j) {
        const float* p = xin + (size_t)csr[j] * D + lane * V;
        if (V == 2) {
            float2 f = *(const float2*)p;
            a0[0] += (double)f.x; a0[1] += (double)f.y;
        } else {
            float4 f = *(const float4*)p;
            a0[0] += (double)f.x; a0[1] += (double)f.y; a0[2] += (double)f.z; a0[3] += (double)f.w;
        }
    }
    double inv = 1.0 / (double)max(s1 - s0, 1);
#pragma unroll
    for (int i = 0; i < V; ++i)
        agg[(size_t)wid * D + lane * V + i] = (float)(((a0[i] + a1[i]) + (a2[i] + a3[i])) * inv);
}

// bf16-source variant (gate-free consumers only), same 4-row unroll
template<int D>
__global__ void k_aggr_bf(const unsigned short* __restrict__ xin, const int* __restrict__ row_ptr,
                          const int* __restrict__ csr, float* __restrict__ agg, int n) {
    int wid = (blockIdx.x * blockDim.x + threadIdx.x) >> 6;
    int lane = threadIdx.x & 63;
    if (wid >= n) return;
    constexpr int V = D / 64;
    double a0[V], a1[V], a2[V], a3[V];
#pragma unroll
    for (int i = 0; i < V; ++i) { a0[i] = 0.0; a1[i] = 0.0; a2[i] = 0.0; a3[i] = 0.0; }
    int s0 = row_ptr[wid], s1 = row_ptr[wid + 1];
    int j = s0;
    for (; j + 4 <= s1; j += 4) {
        int i0 = csr[j], i1 = csr[j + 1], i2 = csr[j + 2], i3 = csr[j + 3];
        uint2 u0 = *(const uint2*)(xin + (size_t)i0 * D + lane * V);
        uint2 u1 = *(const uint2*)(xin + (size_t)i1 * D + lane * V);
        uint2 u2 = *(const uint2*)(xin + (size_t)i2 * D + lane * V);
        uint2 u3 = *(const uint2*)(xin + (size_t)i3 * D + lane * V);
        a0[0] += (double)bflo(u0.x); a0[1] += (double)bfhi(u0.x);
        a0[2] += (double)bflo(u0.y); a0[3] += (double)bfhi(u0.y);
        a1[0] += (double)bflo(u1.x); a1[1] += (double)bfhi(u1.x);
        a1[2] += (double)bflo(u1.y); a1[3] += (double)bfhi(u1.y);
        a2[0] += (double)bflo(u2.x); a2[1] += (double)bfhi(u2.x);
        a2[2] += (double)bflo(u2.y); a2[3] += (double)bfhi(u2.y);
        a3[0] += (double)bflo(u3.x); a3[1] += (double)bfhi(u3.x);
        a3[2] += (double)bflo(u3.y); a3[3] += (double)bfhi(u3.y);
    }
    for (; j < s1; ++j) {
        uint2 u = *(const uint2*)(xin + (size_t)csr[j] * D + lane * V);
        a0[0] += (double)bflo(u.x); a0[1] += (double)bfhi(u.x);
        a0[2] += (double)bflo(u.y); a0[3] += (double)bfhi(u.y);
    }
    double inv = 1.0 / (double)max(s1 - s0, 1);
#pragma unroll
    for (int i = 0; i < V; ++i)
        agg[(size_t)wid * D + lane * V + i] = (float)(((a0[i] + a1[i]) + (a2[i] + a3[i])) * inv);
}

// ---------------- gate (round-5 verbatim; fp32 weights read directly) ----------------
template<int D>
__global__ void k_gate(const float* __restrict__ agg, const float* __restrict__ wg,
                       const float* __restrict__ bg, int* __restrict__ idx,
                       int* __restrict__ ecnt, float* __restrict__ gsum, int n) {
    __shared__ float swg[D * 8];
    __shared__ int hcnt[8];
    __shared__ float red[256];
    int t = threadIdx.x;
    if (t < 8) hcnt[t] = 0;
    for (int i = t; i < D * 8; i += 256) swg[i] = wg[i];
    __syncthreads();
    int nid = blockIdx.x * 256 + t;
    float stdv = 0.f;
    if (nid < n) {
        double lg[8];
#pragma unroll
        for (int e = 0; e < 8; ++e) lg[e] = (double)bg[e];
        const float* ap = agg + (size_t)nid * D;
        for (int k = 0; k < D; k += 4) {
            float4 a = *(const float4*)(ap + k);
#pragma unroll
            for (int e = 0; e < 8; ++e) {
                lg[e] += (double)a.x * swg[(k + 0) * 8 + e] + (double)a.y * swg[(k + 1) * 8 + e]
                       + (double)a.z * swg[(k + 2) * 8 + e] + (double)a.w * swg[(k + 3) * 8 + e];
            }
        }
        double m = lg[0];
        int am = 0;
#pragma unroll
        for (int e = 1; e < 8; ++e) if (lg[e] > m) { m = lg[e]; am = e; }
        double s = 0.0, p[8];
#pragma unroll
        for (int e = 0; e < 8; ++e) { p[e] = exp(lg[e] - m); s += p[e]; }
        double invs = 1.0 / s, sq = 0.0;
#pragma unroll
        for (int e = 0; e < 8; ++e) { double q = p[e] * invs; sq += q * q; }
        stdv = (float)sqrt(fmax(sq - 0.125, 0.0) / 7.0);
        idx[nid] = am;
        atomicAdd(&hcnt[am], 1);
    }
    red[t] = stdv;
    __syncthreads();
    for (int off = 128; off > 0; off >>= 1) {
        if (t < off) red[t] += red[t + off];
        __syncthreads();
    }
    if (t == 0) atomicAdd(gsum, red[0]);
    if (t < 8 && hcnt[t] > 0) atomicAdd(&ecnt[t], hcnt[t]);
}

__global__ void k_offsets(const int* __restrict__ ecnt, int* __restrict__ eoff) {
    if (threadIdx.x == 0 && blockIdx.x == 0) {
        int s = 0;
        for (int e = 0; e < 8; ++e) { eoff[e] = s; s += ecnt[e]; }
        eoff[8] = s;
    }
}

__global__ void k_perm(const int* __restrict__ idx, const int* __restrict__ eoff,
                       int* __restrict__ ecur, int* __restrict__ perm, int n) {
    __shared__ int lcnt[8], lbase[8];
    int t = threadIdx.x;
    if (t < 8) lcnt[t] = 0;
    __syncthreads();
    int nid = blockIdx.x * 256 + t;
    int e = 0, r = 0;
    bool valid = (nid < n);
    if (valid) { e = idx[nid]; r = atomicAdd(&lcnt[e], 1); }
    __syncthreads();
    if (t < 8) lbase[t] = lcnt[t] ? atomicAdd(&ecur[t], lcnt[t]) : 0;
    __syncthreads();
    if (valid) perm[eoff[e] + lbase[e] + r] = nid;
}

// ---------------- VALU fp32 GEMM, layer 1 — B-load double-buffer; FMA order unchanged
// (per-output FMA sequence identical to round-5/round-9 -> h1 bit-identical, gate-safe)
template<int DIN, int NCOL, bool EXPERT, bool RELU>
__global__ __launch_bounds__(256) void k_gemm_f32(
    const float* __restrict__ agg, const float* __restrict__ a2,
    const float* __restrict__ B1, const float* __restrict__ B2,
    const float* __restrict__ bias,
    const int* __restrict__ perm, const int* __restrict__ eoff,
    float* __restrict__ outp, int n) {
    constexpr int CT = NCOL / 4;
    constexpr int RG = 256 / CT;
    constexpr int RPT = 64 / RG;
    __shared__ float a_tile[64 * 64];
    __shared__ int rows[64];
    int t = threadIdx.x;
    int e = 0, base = 0, cnt = n;
    if (EXPERT) { e = blockIdx.y; base = eoff[e]; cnt = eoff[e + 1] - base; }
    int rs = blockIdx.x * 64;
    if (rs >= cnt) return;
    int nrows = min(64, cnt - rs);
    if (t < 64) {
        int j = rs + min(t, nrows - 1);
        rows[t] = EXPERT ? perm[base + j] : j;
    }
    __syncthreads();
    int cg = t % CT, rg = t / CT;
    int cols = cg * 4;
    int sr = t >> 2;
    int sk = (t & 3) * 16;
    int grow = rows[sr];
    const float* B1e = B1 + (EXPERT ? (size_t)e * DIN * NCOL : 0);
    float acc[RPT][4];
#pragma unroll
    for (int r = 0; r < RPT; ++r) { acc[r][0] = 0.f; acc[r][1] = 0.f; acc[r][2] = 0.f; acc[r][3] = 0.f; }

#pragma unroll
    for (int half = 0; half < 2; ++half) {
        const float* B = half ? B2 : B1e;
        const float* Af = half ? a2 : agg;
        for (int kc = 0; kc < DIN; kc += 64) {
            __syncthreads();
            {
                const float4* p = (const float4*)(Af + (size_t)grow * DIN + kc + sk);
                float4* d4 = (float4*)&a_tile[sr * 64 + sk];
                d4[0] = p[0]; d4[1] = p[1]; d4[2] = p[2]; d4[3] = p[3];
            }
            __syncthreads();
            const float* Bp = B + (size_t)kc * NCOL + cols;
            float4 cur[4];
#pragma unroll
            for (int kk = 0; kk < 4; ++kk) cur[kk] = *(const float4*)(Bp + (size_t)kk * NCOL);
#pragma unroll
            for (int k = 0; k < 64; k += 4) {
                float4 nxt[4];
                if (k < 60) {
#pragma unroll
                    for (int kk = 0; kk < 4; ++kk)
                        nxt[kk] = *(const float4*)(Bp + (size_t)(k + 4 + kk) * NCOL);
                }
                float bx[4][4];
#pragma unroll
                for (int kk = 0; kk < 4; ++kk) {
                    bx[kk][0] = cur[kk].x; bx[kk][1] = cur[kk].y;
                    bx[kk][2] = cur[kk].z; bx[kk][3] = cur[kk].w;
                }
#pragma unroll
                for (int r = 0; r < RPT; ++r) {
                    float4 a = *(const float4*)&a_tile[(rg * RPT + r) * 64 + k];
#pragma unroll
                    for (int c = 0; c < 4; ++c) {
                        acc[r][c] = fmaf(a.x, bx[0][c], acc[r][c]);
                        acc[r][c] = fmaf(a.y, bx[1][c], acc[r][c]);
                        acc[r][c] = fmaf(a.z, bx[2][c], acc[r][c]);
                        acc[r][c] = fmaf(a.w, bx[3][c], acc[r][c]);
                    }
                }
                if (k < 60) {
#pragma unroll
                    for (int kk = 0; kk < 4; ++kk) cur[kk] = nxt[kk];
                }
            }
        }
    }
    float4 bb = *(const float4*)(bias + (EXPERT ? e * NCOL : 0) + cols);
#pragma unroll
    for (int r = 0; r < RPT; ++r) {
        int rr = rg * RPT + r;
        if (rr < nrows) {
            int gr = rows[rr];
            float v0 = acc[r][0] + bb.x, v1 = acc[r][1] + bb.y;
            float v2 = acc[r][2] + bb.z, v3 = acc[r][3] + bb.w;
            if (RELU) { v0 = fmaxf(v0, 0.f); v1 = fmaxf(v1, 0.f); v2 = fmaxf(v2, 0.f); v3 = fmaxf(v3, 0.f); }
            *(float4*)(outp + (size_t)gr * NCOL + cols) = make_float4(v0, v1, v2, v3);
        }
    }
}

// ---------------- MFMA GEMM (layers 2/3). MODE 0: fp32 A -> f2bf in LDS.
// MODE 2: A already bf16, direct stage (same element mapping, same bits).
template<int DIN, int MODE, int CT>
DEV void gemm_half(const void* __restrict__ Asrc, const unsigned short* __restrict__ BT,
                   short (*Ah)[40], short (*Bs)[40],
                   const int* rows, f32x4 (&acc)[4][CT], int t, int lane, int w) {
    int q = lane >> 4, m16 = lane & 15;
    int r = t >> 2, part = t & 3;
    for (int kc = 0; kc < DIN; kc += 32) {
        __syncthreads();
        if (MODE == 2) {
            *(uint4*)&Ah[r][part * 8] =
                *(const uint4*)((const unsigned short*)Asrc + (size_t)rows[r] * DIN + kc + part * 8);
        } else {
            const float* pf = (const float*)Asrc + (size_t)rows[r] * DIN + kc + part * 8;
            float4 p0 = *(const float4*)pf, p1 = *(const float4*)(pf + 4);
            float va[8] = { p0.x, p0.y, p0.z, p0.w, p1.x, p1.y, p1.z, p1.w };
            short8 h;
#pragma unroll
            for (int j = 0; j < 8; ++j) h[j] = (short)f2bf(va[j]);
            *(short8*)&Ah[r][part * 8] = h;
        }
#pragma unroll
        for (int j = 0; j < CT; ++j) {
            int c = t + 256 * j;
            int nn = c >> 2, pp = c & 3;
            *(uint4*)&Bs[nn][pp * 8] = *(const uint4*)(BT + (size_t)nn * DIN + kc + pp * 8);
        }
        __syncthreads();
        short8 af[4], bfr[CT];
#pragma unroll
        for (int rt = 0; rt < 4; ++rt) af[rt] = *(short8*)&Ah[rt * 16 + m16][q * 8];
#pragma unroll
        for (int ct = 0; ct < CT; ++ct) bfr[ct] = *(short8*)&Bs[w * CT * 16 + ct * 16 + m16][q * 8];
#pragma unroll
        for (int rt = 0; rt < 4; ++rt)
#pragma unroll
            for (int ct = 0; ct < CT; ++ct)
                acc[rt][ct] = __builtin_amdgcn_mfma_f32_16x16x32_bf16(af[rt], bfr[ct], acc[rt][ct], 0, 0, 0);
    }
}

// OUTBF=true -> bf16 store (intermediate h2b); false -> fp32 store (d_out is fp32)
template<int DIN, int M0, int M1, int CT, bool EXPERT, bool RELU, bool OUTBF>
__global__ __launch_bounds__(256) void k_gemm(
    const void* __restrict__ A0, const void* __restrict__ A1,
    const unsigned short* __restrict__ B0T, const unsigned short* __restrict__ B1T,
    const float* __restrict__ bias,
    const int* __restrict__ perm, const int* __restrict__ eoff,
    void* __restrict__ outp, int n) {
    constexpr int NCOL = CT * 64;
    __shared__ short Ah[64][40];
    __shared__ short Bs[NCOL][40];
    __shared__ int rows[64];
    int t = threadIdx.x;
    int lane = t & 63, w = t >> 6;
    int e = 0, base = 0, cnt = n;
    if (EXPERT) { e = blockIdx.y; base = eoff[e]; cnt = eoff[e + 1] - base; }
    int rs = blockIdx.x * 64;
    if (rs >= cnt) return;
    int nrows = min(64, cnt - rs);
    if (t < 64) {
        int j = rs + min(t, nrows - 1);
        rows[t] = EXPERT ? perm[base + j] : j;
    }
    __syncthreads();
    f32x4 acc[4][CT];
#pragma unroll
    for (int rt = 0; rt < 4; ++rt)
#pragma unroll
        for (int ct = 0; ct < CT; ++ct) acc[rt][ct] = (f32x4)(0.f);

    gemm_half<DIN, M0, CT>(A0, B0T + (EXPERT ? (size_t)e * DIN * NCOL : 0), Ah, Bs, rows, acc, t, lane, w);
    gemm_half<DIN, M1, CT>(A1, B1T, Ah, Bs, rows, acc, t, lane, w);

    int q = lane >> 4, m16 = lane & 15;
#pragma unroll
    for (int ct = 0; ct < CT; ++ct) {
        int col = w * CT * 16 + ct * 16 + m16;
        float bv = bias[(EXPERT ? e * NCOL : 0) + col];
#pragma unroll
        for (int rt = 0; rt < 4; ++rt)
#pragma unroll
            for (int i = 0; i < 4; ++i) {
                int rr = rt * 16 + q * 4 + i;
                if (rr < nrows) {
                    int gr = rows[rr];
                    float v = acc[rt][ct][i] + bv;
                    if (RELU) v = fmaxf(v, 0.f);
                    if (OUTBF) ((unsigned short*)outp)[(size_t)gr * NCOL + col] = f2bf(v);
                    else       ((float*)outp)[(size_t)gr * NCOL + col] = v;
                }
            }
    }
}

__global__ void k_final(const float* __restrict__ gsum, float* __restrict__ outf) {
    if (threadIdx.x == 0 && blockIdx.x == 0) {
        float g = (gsum[0] + gsum[1]) * (0.5f / 50000.0f);
        outf[(size_t)50000 * 128] = g;   // output buffer is fp32
    }
}

extern "C" void kernel_launch(void* const* d_in, const int* in_sizes, int n_in,
                              void* d_out, int out_size, void* d_ws, size_t ws_size,
                              hipStream_t stream) {
    constexpr int N = 50000, E = 800000;
    const float* x   = (const float*)d_in[0];
    const int* ei    = (const int*)d_in[1];
    const float* wg1 = (const float*)d_in[2];
    const float* bg1 = (const float*)d_in[3];
    const float* we1 = (const float*)d_in[4];
    const float* be1 = (const float*)d_in[5];
    const float* wr1 = (const float*)d_in[6];
    const float* wg2 = (const float*)d_in[7];
    const float* bg2 = (const float*)d_in[8];
    const float* we2 = (const float*)d_in[9];
    const float* be2 = (const float*)d_in[10];
    const float* wr2 = (const float*)d_in[11];
    const float* wl3 = (const float*)d_in[12];
    const float* bl3 = (const float*)d_in[13];
    const float* wr3 = (const float*)d_in[14];

    // ---- workspace layout ----
    int* ip = (int*)d_ws;
    int* deg = ip;            ip += N;
    int* cursor = ip;         ip += N;
    int* ecnt = ip;           ip += 16;
    int* ecur = ip;           ip += 16;
    float* gsum = (float*)ip; ip += 2;
    int* flags = ip;          ip += 2;
    int* row_ptr = ip;        ip += N + 1;
    int* csr = ip;            ip += E;
    int* idxb = ip;           ip += N;
    int* permb = ip;          ip += N;
    int* eoff = ip;           ip += 18;
    int* part = ip;           ip += 256;
    int* src32 = ip;          ip += E;
    int* dst32 = ip;          ip += E;
    size_t off = (size_t)((char*)ip - (char*)d_ws);
    off = (off + 255) & ~(size_t)255;
    float* fp = (float*)((char*)d_ws + off);
    float* agg = fp; fp += (size_t)N * 256;            // fp32 agg (layers 1-3)
    float* h1  = fp; fp += (size_t)N * 256;            // fp32 h1 (gate-2 critical)
    unsigned short* wp = (unsigned short*)fp;
    unsigned short* h2b  = wp; wp += (size_t)N * 256;  // bf16 h2 (gate-free)
    unsigned short* we2T = wp; wp += 8 * 256 * 256;    // bf16 B^T [n][k]
    unsigned short* wr2T = wp; wp += 256 * 256;
    unsigned short* wl3T = wp; wp += 256 * 128;
    unsigned short* wr3T = wp; wp += 256 * 128;

    hipMemsetAsync(d_ws, 0, (size_t)(2 * N + 36) * 4, stream);

    k_detect<<<1, 64, 0, stream>>>(ei, flags);
    k_cvt_idx<<<(E + 255) / 256, 256, 0, stream>>>(ei, src32, dst32, E, flags);

    // fused transpose+narrow to bf16 B^T [n][k] (layers 2/3)
    k_transpose_nb<<<dim3(8, 8, 8), 256, 0, stream>>>(we2, we2T, 256, 256);
    k_transpose_nb<<<dim3(8, 8, 1), 256, 0, stream>>>(wr2, wr2T, 256, 256);
    k_transpose_nb<<<dim3(4, 8, 1), 256, 0, stream>>>(wl3, wl3T, 256, 128);
    k_transpose_nb<<<dim3(4, 8, 1), 256, 0, stream>>>(wr3, wr3T, 256, 128);

    // CSR
    constexpr int NB = (N + 255) / 256;
    constexpr int WB = (N + 3) / 4;
    k_degree<<<(E + 255) / 256, 256, 0, stream>>>(dst32, deg, E);
    k_scan1<<<NB, 256, 0, stream>>>(deg, row_ptr, part, N);
    k_scan2<<<1, 256, 0, stream>>>(part, NB);
    k_scan3<<<NB, 256, 0, stream>>>(row_ptr, part, N, E);
    k_fill<<<(E + 255) / 256, 256, 0, stream>>>(src32, dst32, row_ptr, cursor, csr, E);

    constexpr int GB = (N + 63) / 64;
    // ---- layer 1: 128 -> 256, MoE + root(x), relu — VALU fp32 (h1 bit-identical) ----
    k_aggr<128><<<WB, 256, 0, stream>>>(x, row_ptr, csr, agg, N);
    k_gate<128><<<NB, 256, 0, stream>>>(agg, wg1, bg1, idxb, ecnt, gsum, N);
    k_offsets<<<1, 1, 0, stream>>>(ecnt, eoff);
    k_perm<<<NB, 256, 0, stream>>>(idxb, eoff, ecur, permb, N);
    k_gemm_f32<128, 256, true, true><<<dim3(GB, 8), 256, 0, stream>>>(
        agg, x, we1, wr1, be1, permb, eoff, h1, N);

    // ---- layer 2: 256 -> 256, MoE + root(h1), relu — MFMA MODE 0; bf16 h2b out ----
    k_aggr<256><<<WB, 256, 0, stream>>>(h1, row_ptr, csr, agg, N);  // fp32 gather (gate feeds)
    k_gate<256><<<NB, 256, 0, stream>>>(agg, wg2, bg2, idxb, ecnt + 8, gsum + 1, N);
    k_offsets<<<1, 1, 0, stream>>>(ecnt + 8, eoff + 9);
    k_perm<<<NB, 256, 0, stream>>>(idxb, eoff + 9, ecur + 8, permb, N);
    k_gemm<256, 0, 0, 4, true, true, true><<<dim3(GB, 8), 256, 0, stream>>>(
        agg, h1, we2T, wr2T, be2, permb, eoff + 9, h2b, N);

    // ---- layer 3: plain SAGE 256 -> 128 — bf16 gather (no gate), MFMA; fp32 out ----
    k_aggr_bf<256><<<WB, 256, 0, stream>>>(h2b, row_ptr, csr, agg, N);
    k_gemm<256, 0, 2, 2, false, false, false><<<dim3(GB, 1), 256, 0, stream>>>(
        agg, h2b, wl3T, wr3T, bl3, nullptr, nullptr, d_out, N);

    k_final<<<1, 1, 0, stream>>>(gsum, (float*)d_out);
}